// Round 11
// baseline (599.344 us; speedup 1.0000x reference)
//
#include <hip/hip_runtime.h>
#include <hip/hip_bf16.h>
#include <hip/hip_cooperative_groups.h>
#include <cstdint>
#include <cstddef>

namespace cg = cooperative_groups;

// Problem constants
static constexpr int B   = 1024;
static constexpr int N   = 64;
static constexpr int BN  = B * N;      // 65536 nodes
static constexpr int EPG = 192;
static constexpr int E   = B * EPG;    // 196608 edges
static constexpr int FP  = 608;        // padded feature dim (mult of 32)
static constexpr int KP1 = 320;        // conv1 K (PX0 cols, padded)
static constexpr int PMS = 80;         // Pm row stride (bf16)
static constexpr int NCONV = 2560;     // conv blocks per conv dispatch

typedef __hip_bfloat16 bf16;
typedef __bf16 bf16x8 __attribute__((ext_vector_type(8)));
typedef __bf16 bf16x4 __attribute__((ext_vector_type(4)));
typedef float  f32x4  __attribute__((ext_vector_type(4)));

__device__ __forceinline__ void storeC(float* p, float v) { *p = v; }
__device__ __forceinline__ void storeC(bf16* p, float v) { *p = __float2bfloat16(v); }

// async global->LDS, 16B per lane; LDS dest is wave-uniform base + lane*16
__device__ __forceinline__ void llds16(const void* g, void* l) {
    __builtin_amdgcn_global_load_lds(
        (const __attribute__((address_space(1))) unsigned int*)g,
        (__attribute__((address_space(3))) unsigned int*)l,
        16, 0, 0);
}

// ===========================================================================
// 64x128 MFMA GEMM tile body: C[64 x 128 at (m0,n0)] = A @ Bt^T (+bias)(relu)
// (film).  4 waves each 64x32.  As: 4KB, Bs: 8KB.
// ===========================================================================
template<bool RELU, bool FILM, typename CT>
__device__ __forceinline__ void g64_tile(
    const bf16* __restrict__ A, int lda,
    const bf16* __restrict__ Bt, int ldb,
    const float* __restrict__ bias,
    CT* __restrict__ C, int ldc, int Ncap,
    const bf16* __restrict__ fS, const bf16* __restrict__ fT, int fstride,
    int K, int m0, int n0, __bf16* As, __bf16* Bs, int tid)
{
    const int lane = tid & 63;
    const int w    = tid >> 6;
    const int wn   = w * 32;
    const int l15  = lane & 15;
    const int lhi  = lane >> 4;

    f32x4 acc[4][2] = {};

    for (int k0 = 0; k0 < K; k0 += 32) {
        {   // A tile: 256 chunks of 16B
            int row = tid >> 2, kc = tid & 3;
            char* la = (char*)As + (size_t)(w * 64) * 16;
            llds16(A + (size_t)(m0 + row) * lda + k0 + kc * 8, la);
        }
        #pragma unroll
        for (int t = 0; t < 2; ++t) {   // B tile: 512 chunks
            int ci  = t * 256 + tid;
            int row = ci >> 2, kc = ci & 3;
            char* lb = (char*)Bs + (size_t)(t * 256 + w * 64) * 16;
            llds16(Bt + (size_t)(n0 + row) * ldb + k0 + kc * 8, lb);
        }
        asm volatile("s_waitcnt vmcnt(0)" ::: "memory");
        __syncthreads();

        bf16x8 af[4], bg[2];
        #pragma unroll
        for (int i = 0; i < 4; ++i)
            af[i] = *(bf16x8*)(As + (i * 16 + l15) * 32 + lhi * 8);
        #pragma unroll
        for (int j = 0; j < 2; ++j)
            bg[j] = *(bf16x8*)(Bs + (wn + j * 16 + l15) * 32 + lhi * 8);
        #pragma unroll
        for (int i = 0; i < 4; ++i)
            #pragma unroll
            for (int j = 0; j < 2; ++j)
                acc[i][j] = __builtin_amdgcn_mfma_f32_16x16x32_bf16(
                    af[i], bg[j], acc[i][j], 0, 0, 0);
        __syncthreads();
    }

    #pragma unroll
    for (int i = 0; i < 4; ++i) {
        #pragma unroll
        for (int j = 0; j < 2; ++j) {
            int col = n0 + wn + j * 16 + l15;
            if (col < Ncap) {
                float bv = bias ? bias[col] : 0.f;
                #pragma unroll
                for (int e = 0; e < 4; ++e) {
                    int row = m0 + i * 16 + lhi * 4 + e;
                    float v = acc[i][j][e] + bv;
                    if (RELU) v = fmaxf(v, 0.f);
                    if (FILM) {
                        float sv = __bfloat162float(fS[(size_t)row * fstride + col]);
                        float tv = __bfloat162float(fT[(size_t)row * fstride + col]);
                        v = v * (1.f + sv) + tv;
                    }
                    storeC(&C[(size_t)row * ldc + col], v);
                }
            }
        }
    }
}

// noinline guest wrappers: keep guest register usage from inflating host VGPRs
__device__ __attribute__((noinline)) void guest_g64(
    const bf16* gA, int glda, const bf16* gBt, int gldb,
    const float* gbias, bf16* gC, int gldc, int gNcap, int gK, int gnt,
    int t, char* lds, int tid)
{
    int mt2 = t / gnt, nt2 = t % gnt;
    g64_tile<true, false, bf16>(gA, glda, gBt, gldb, gbias, gC, gldc, gNcap,
                                nullptr, nullptr, 0, gK, mt2 * 64, nt2 * 128,
                                (__bf16*)lds, (__bf16*)(lds + 4096), tid);
}

struct WtJob { const float* src; bf16* dst; int Ksrc, Nsrc, Kp, Np, blk0; };

// LDS-tiled coalesced transpose: dst[n][k] = src[k][n] (fp32->bf16).  16.7KB LDS.
__device__ __attribute__((noinline)) void guest_wt(WtJob jb, int t, char* lds, int tid)
{
    int kt = (jb.Kp + 63) >> 6;
    int ti = t % kt, tj = t / kt;
    int kg0 = ti * 64, ng0 = tj * 64;
    float (*T)[65] = (float(*)[65])lds;
    #pragma unroll 4
    for (int r = 0; r < 16; ++r) {
        int kl = (tid >> 6) + r * 4, nl = tid & 63;
        int kg = kg0 + kl, ng = ng0 + nl;
        T[kl][nl] = (kg < jb.Ksrc && ng < jb.Nsrc)
                    ? jb.src[(size_t)kg * jb.Nsrc + ng] : 0.f;
    }
    __syncthreads();
    #pragma unroll 4
    for (int r = 0; r < 16; ++r) {
        int nl = (tid >> 6) + r * 4, kl = tid & 63;
        int ng = ng0 + nl, kg = kg0 + kl;
        if (ng < jb.Np && kg < jb.Kp)
            jb.dst[(size_t)ng * jb.Kp + kg] = __float2bfloat16(T[kl][nl]);
    }
}

// per-graph pair prep: P row-half of Pmg + q vector.  Exactly 17408 B LDS.
__device__ __attribute__((noinline)) void guest_pp(
    const int* ei, bf16* Pmg, float* qv, int g, char* lds, int tid)
{
    float* Pf   = (float*)lds;              // 64*64 fp32 = 16384
    int*   cnt  = (int*)  (lds + 16384);    // 64 (+pad)
    float* sI   = (float*)(lds + 16640);
    float* sIvd = (float*)(lds + 16896);
    float* sQ   = (float*)(lds + 17152);

    for (int i = tid; i < 4096; i += 256) Pf[i] = 0.f;
    if (tid < 64) cnt[tid] = 0;
    __syncthreads();
    if (tid < EPG) atomicAdd(&cnt[ei[E + g * EPG + tid] & 63], 1);
    __syncthreads();
    if (tid < 64) {
        float d = (float)cnt[tid] + 1.f;
        float iv = 1.f / d;
        sIvd[tid] = iv;
        sI[tid]   = rsqrtf(d);
        sQ[tid]   = iv;
    }
    __syncthreads();
    if (tid < EPG) {
        int ls = ei[g * EPG + tid] & 63;
        int ld = ei[E + g * EPG + tid] & 63;
        float cf = sI[ls] * sI[ld];
        atomicAdd(&Pf[ld * 64 + ls], cf);
        atomicAdd(&sQ[ls], cf);
    }
    __syncthreads();
    if (tid < 64) {
        Pf[tid * 64 + tid] += sIvd[tid];
        qv[g * 64 + tid] = sQ[tid] * (1.f / 64.f);
    }
    __syncthreads();
    int pr = g >> 1, half = g & 1;
    for (int idx = tid; idx < 64 * PMS; idx += 256) {
        int r = idx / PMS, k = idx - r * PMS;
        float v = (k < 64) ? Pf[r * 64 + k] : 0.f;
        Pmg[(size_t)pr * (128 * PMS) + (size_t)(half * 64 + r) * PMS + k]
            = __float2bfloat16(v);
    }
}

// ===========================================================================
// conv1 as plain GEMM + guests: t1-GEMM, 7 weight transposes, pair-prep.
// ===========================================================================
struct Conv1Args {
    const bf16* A; const bf16* Bt; const float* bias; bf16* X1;
    const bf16* TE; const bf16* Wt1t; const float* b_t1; bf16* A1b;
    WtJob wj[7];
    const int* ei; bf16* Pmg; float* qv;
    int t1_end, wt_end;            // region ends (block index, after NCONV)
};

__global__ __launch_bounds__(256) void conv1_gemm(Conv1Args a)
{
    __shared__ __align__(16) char regA[17408];
    const int tid = threadIdx.x;
    const int bid = blockIdx.x;

    if (bid >= NCONV) {
        int t = bid - NCONV;
        if (t < a.t1_end) {
            guest_g64(a.TE, 128, a.Wt1t, 128, a.b_t1, a.A1b, 512, 512, 128, 4,
                      t, regA, tid);
        } else if (t < a.wt_end) {
            int tw = t - a.t1_end;
            int ji = 0;
            while (ji < 6 && tw >= a.wj[ji + 1].blk0) ++ji;
            guest_wt(a.wj[ji], tw - a.wj[ji].blk0, regA, tid);
        } else {
            guest_pp(a.ei, a.Pmg, a.qv, t - a.wt_end, regA, tid);
        }
        return;
    }

    __bf16* As = (__bf16*)regA;
    __bf16* Bs = (__bf16*)(regA + 8192);

    const int lane = tid & 63;
    const int w    = tid >> 6;
    const int wm   = (w & 1) * 64;
    const int wn   = (w >> 1) * 64;
    const int l15  = lane & 15;
    const int lhi  = lane >> 4;

    const int lid = bid >> 3;
    const int mt  = (bid & 7) * 64 + lid / 5;
    const int nt  = lid % 5;
    const int m0  = mt * 128;
    const int n0  = nt * 128;

    f32x4 acc[4][4] = {};
    for (int k0 = 0; k0 < KP1; k0 += 32) {
        #pragma unroll
        for (int t = 0; t < 2; ++t) {
            int ci  = t * 256 + w * 64 + lane;
            int row = ci >> 2, kc = ci & 3;
            char* la = (char*)As + (size_t)(t * 256 + w * 64) * 16;
            char* lb = (char*)Bs + (size_t)(t * 256 + w * 64) * 16;
            llds16(a.A  + (size_t)(m0 + row) * KP1 + k0 + kc * 8, la);
            llds16(a.Bt + (size_t)(n0 + row) * KP1 + k0 + kc * 8, lb);
        }
        asm volatile("s_waitcnt vmcnt(0)" ::: "memory");
        __syncthreads();

        bf16x8 af[4], bg[4];
        #pragma unroll
        for (int i = 0; i < 4; ++i)
            af[i] = *(bf16x8*)(As + (wm + i * 16 + l15) * 32 + lhi * 8);
        #pragma unroll
        for (int j = 0; j < 4; ++j)
            bg[j] = *(bf16x8*)(Bs + (wn + j * 16 + l15) * 32 + lhi * 8);
        #pragma unroll
        for (int i = 0; i < 4; ++i)
            #pragma unroll
            for (int j = 0; j < 4; ++j)
                acc[i][j] = __builtin_amdgcn_mfma_f32_16x16x32_bf16(
                    af[i], bg[j], acc[i][j], 0, 0, 0);
        __syncthreads();
    }

    #pragma unroll
    for (int i = 0; i < 4; ++i)
        #pragma unroll
        for (int j = 0; j < 4; ++j) {
            int col = n0 + wn + j * 16 + l15;
            if (col < FP) {
                float bv = (col < 600) ? a.bias[col] : 0.f;
                #pragma unroll
                for (int e = 0; e < 4; ++e) {
                    int row = m0 + wm + i * 16 + lhi * 4 + e;
                    float v = fmaxf(acc[i][j][e] + bv, 0.f);
                    a.X1[(size_t)row * FP + col] = __float2bfloat16(v);
                }
            }
        }
}

// ===========================================================================
// conv2+conv3+pool fused (+ hidden t2 via noinline guest).  Writes only Y.
// ===========================================================================
__global__ __launch_bounds__(256) void conv_fused_q(
    const bf16* __restrict__ A, int lda, int K,
    const bf16* __restrict__ Bt, int ldb,
    const bf16* __restrict__ Pmg,
    const float* __restrict__ bias,
    const float* __restrict__ qv,
    bf16* __restrict__ Y,
    const bf16* __restrict__ gA, int glda,
    const bf16* __restrict__ gBt, int gldb,
    const float* __restrict__ gbias,
    bf16* __restrict__ gC, int gldc, int gNcap, int gK, int gnt)
{
    __shared__ __align__(16) char regA[17408];
    __shared__ __align__(16) __bf16 Pm[128 * PMS];
    __shared__ float s_q[128];

    const int tid = threadIdx.x;
    const int bid = blockIdx.x;

    if (bid >= NCONV) {
        guest_g64(gA, glda, gBt, gldb, gbias, gC, gldc, gNcap, gK, gnt,
                  bid - NCONV, regA, tid);
        return;
    }

    __bf16* As = (__bf16*)regA;
    __bf16* Bs = (__bf16*)(regA + 8192);
    __bf16* Ts = (__bf16*)regA;

    const int lane = tid & 63;
    const int w    = tid >> 6;
    const int wm   = (w & 1) * 64;
    const int wn   = (w >> 1) * 64;
    const int l15  = lane & 15;
    const int lhi  = lane >> 4;

    const int lid = bid >> 3;
    const int mt  = (bid & 7) * 64 + lid / 5;
    const int nt  = lid % 5;
    const int m0  = mt * 128;
    const int n0  = nt * 128;

    #pragma unroll
    for (int i = 0; i < 5; ++i) {
        int cbase = w * 320 + i * 64;
        llds16(Pmg + (size_t)mt * (128 * PMS) + (size_t)(cbase + lane) * 8,
               (char*)Pm + (size_t)cbase * 16);
    }
    if (tid < 128) s_q[tid] = qv[mt * 128 + tid];

    f32x4 acc[4][4] = {};
    for (int k0 = 0; k0 < K; k0 += 32) {
        #pragma unroll
        for (int t = 0; t < 2; ++t) {
            int ci  = t * 256 + w * 64 + lane;
            int row = ci >> 2, kc = ci & 3;
            char* la = (char*)As + (size_t)(t * 256 + w * 64) * 16;
            char* lb = (char*)Bs + (size_t)(t * 256 + w * 64) * 16;
            llds16(A  + (size_t)(m0 + row) * lda + k0 + kc * 8, la);
            llds16(Bt + (size_t)(n0 + row) * ldb + k0 + kc * 8, lb);
        }
        asm volatile("s_waitcnt vmcnt(0)" ::: "memory");
        __syncthreads();

        bf16x8 af[4], bg[4];
        #pragma unroll
        for (int i = 0; i < 4; ++i)
            af[i] = *(bf16x8*)(As + (wm + i * 16 + l15) * 32 + lhi * 8);
        #pragma unroll
        for (int j = 0; j < 4; ++j)
            bg[j] = *(bf16x8*)(Bs + (wn + j * 16 + l15) * 32 + lhi * 8);
        #pragma unroll
        for (int i = 0; i < 4; ++i)
            #pragma unroll
            for (int j = 0; j < 4; ++j)
                acc[i][j] = __builtin_amdgcn_mfma_f32_16x16x32_bf16(
                    af[i], bg[j], acc[i][j], 0, 0, 0);
        __syncthreads();
    }

    const int g  = w & 1;
    const int nb = w >> 1;
    #pragma unroll
    for (int h = 0; h < 2; ++h) {
        if (wn == h * 64) {
            #pragma unroll
            for (int i = 0; i < 4; ++i)
                #pragma unroll
                for (int j = 0; j < 4; ++j) {
                    int c_local = j * 16 + l15;
                    int rbase   = wm + i * 16 + lhi * 4;
                    bf16x4 pk;
                    #pragma unroll
                    for (int e = 0; e < 4; ++e) pk[e] = (__bf16)acc[i][j][e];
                    *(bf16x4*)(Ts + c_local * 136 + rbase) = pk;
                }
        }
        __syncthreads();

        f32x4 acc2[4][2] = {};
        #pragma unroll
        for (int k0 = 0; k0 < 64; k0 += 32) {
            bf16x8 pa[4], hb[2];
            #pragma unroll
            for (int i = 0; i < 4; ++i)
                pa[i] = *(bf16x8*)(Pm + (g * 64 + i * 16 + l15) * PMS + k0 + lhi * 8);
            #pragma unroll
            for (int j = 0; j < 2; ++j)
                hb[j] = *(bf16x8*)(Ts + (nb * 32 + j * 16 + l15) * 136
                                      + g * 64 + k0 + lhi * 8);
            #pragma unroll
            for (int i = 0; i < 4; ++i)
                #pragma unroll
                for (int j = 0; j < 2; ++j)
                    acc2[i][j] = __builtin_amdgcn_mfma_f32_16x16x32_bf16(
                        pa[i], hb[j], acc2[i][j], 0, 0, 0);
        }
        #pragma unroll
        for (int j = 0; j < 2; ++j) {
            int col = n0 + h * 64 + nb * 32 + j * 16 + l15;
            float bv = (col < 600) ? bias[col] : 0.f;
            float yp = 0.f;
            #pragma unroll
            for (int i = 0; i < 4; ++i)
                #pragma unroll
                for (int e = 0; e < 4; ++e) {
                    float v = fmaxf(acc2[i][j][e] + bv, 0.f);   // relu
                    yp += s_q[g * 64 + i * 16 + lhi * 4 + e] * v;
                }
            yp += __shfl_xor(yp, 16, 64);
            yp += __shfl_xor(yp, 32, 64);
            if (lhi == 0 && col < FP)
                Y[(size_t)(mt * 2 + g) * FP + col] = __float2bfloat16(yp);
        }
        __syncthreads();
    }
}

// ===========================================================================
// prep_a: [Wc1/Wt1 transposes | timestep emb | PX0 commute branch]
// ===========================================================================
struct PrepAArgs {
    WtJob j[2];
    int nwt, te0;                  // te0 = nwt; px0 region starts te0+512
    const int*   ei;
    const float* ts;
    const float* xin; const float* Wtr; const float* btr; const float* mask;
    bf16* TE; bf16* PX0;
};

__global__ __launch_bounds__(256) void prep_a(PrepAArgs a)
{
    __shared__ __align__(16) char sm[35840];
    const int bx  = blockIdx.x;
    const int tid = threadIdx.x;

    if (bx < a.nwt) {
        int ji = (bx >= a.j[1].blk0) ? 1 : 0;
        guest_wt(a.j[ji], bx - a.j[ji].blk0, sm, tid);
    } else if (bx < a.te0 + 512) {
        int idx = (bx - a.te0) * 256 + tid;
        int b = idx >> 7, jj = idx & 127;
        float tt = a.ts[b];
        int h = jj & 63;
        float freq = expf(-9.210340371976184f * (float)h / 64.f);  // ln(10000)
        float ang = tt * freq;
        a.TE[idx] = __float2bfloat16((jj < 64) ? cosf(ang) : sinf(ang));
    } else {
        // ---------- PX0 branch (per graph): PX0 = xa@Wtr + ba*b^T ----------
        int g = bx - (a.te0 + 512);
        float* Pf  = (float*)sm;                 // 64*64 fp32; Ws overlays later
        float* Ws  = (float*)sm;                 // 19*304 fp32
        float* xm  = (float*)(sm + 23104);       // 64*20 (col 19 = mask)
        float* xa  = (float*)(sm + 28224);       // 64*20 (col 19 = ba)
        float* isqv= (float*)(sm + 33344);
        float* ivdv= (float*)(sm + 33600);
        int*   cnt = (int*)  (sm + 33856);
        float* sb  = (float*)(sm + 34112);       // 304

        for (int idx = tid; idx < 4096; idx += 256) Pf[idx] = 0.f;
        if (tid < 64) cnt[tid] = 0;
        __syncthreads();
        if (tid < EPG) atomicAdd(&cnt[a.ei[E + g * EPG + tid] & 63], 1);
        __syncthreads();
        if (tid < 64) {
            float d = (float)cnt[tid] + 1.0f;
            ivdv[tid] = 1.f / d;
            isqv[tid] = rsqrtf(d);
        }
        __syncthreads();
        if (tid < EPG) {
            int ls = a.ei[g * EPG + tid] & 63;
            int ld = a.ei[E + g * EPG + tid] & 63;
            atomicAdd(&Pf[ld * 64 + ls], isqv[ls] * isqv[ld]);
        }
        for (int idx = tid; idx < 64 * 20; idx += 256) {
            int n = idx / 20, j = idx - n * 20;
            float mv = a.mask[g * 64 + n];
            xm[idx] = (j < 19) ? mv * a.xin[(size_t)(g * 64 + n) * 19 + j] : mv;
        }
        __syncthreads();
        if (tid < 64) Pf[tid * 64 + tid] += ivdv[tid];
        __syncthreads();
        for (int idx = tid; idx < 64 * 20; idx += 256) {
            int r = idx / 20, j = idx - r * 20;
            float s = 0.f;
            #pragma unroll 8
            for (int s2 = 0; s2 < 64; ++s2)
                s += Pf[r * 64 + s2] * xm[s2 * 20 + j];
            xa[idx] = s;
        }
        __syncthreads();
        for (int idx = tid; idx < 19 * 304; idx += 256) {
            int k = idx / 304, c = idx - k * 304;
            Ws[idx] = (c < 300) ? a.Wtr[k * 300 + c] : 0.f;
        }
        for (int c = tid; c < 304; c += 256)
            sb[c] = (c < 300) ? a.btr[c] : 0.f;
        __syncthreads();
        int n  = tid >> 2;
        int c0 = tid & 3;
        float ba = xa[n * 20 + 19];
        for (int c = c0; c < 304; c += 4) {
            float acc = ba * sb[c];
            #pragma unroll
            for (int k = 0; k < 19; ++k)
                acc += xa[n * 20 + k] * Ws[k * 304 + c];
            a.PX0[(size_t)(g * 64 + n) * KP1 + c] = __float2bfloat16(acc);
        }
        bf16x8 z = {};
        for (int idx = tid; idx < 64 * 2; idx += 256) {
            int nn = idx >> 1, jv = idx & 1;
            *(bf16x8*)((__bf16*)a.PX0 + (size_t)(g * 64 + nn) * KP1 + 304 + jv * 8) = z;
        }
    }
}

// ===========================================================================
// Cooperative tail: [EO || G0] -> h1 -> h2 -> h3 -> ln+copy, one dispatch.
// grid 384 x 256, LDS ~12.3 KB -> all blocks co-resident.
// ===========================================================================
struct TailArgs {
    const bf16* A2b; const bf16* Wet; const float* b_e; bf16* EO;
    const bf16* Yv;  const bf16* Wb3; const float* b_c3; bf16* G0;
    const bf16* Wh1t; const float* b_h1; bf16* G1;
    const bf16* Wh2t; const float* b_h2; bf16* G2;
    const bf16* Wh3t; const float* b_h3; float* G3;
    const float* ln_g; const float* ln_b; const float* text; float* out;
};

__global__ __launch_bounds__(256) void k_tail(TailArgs a)
{
    __shared__ __align__(16) __bf16 As[64 * 32];
    __shared__ __align__(16) __bf16 Bs[128 * 32];
    __shared__ float red[4];
    __shared__ float smu, svar;

    cg::grid_group grid = cg::this_grid();
    const int bid = blockIdx.x;
    const int tid = threadIdx.x;

    // P0: EO (384 tiles) || G0 (80 tiles), strided over 384 blocks
    for (int t = bid; t < 464; t += 384) {
        if (t < 384) {
            int mt = t / 24, nt = t % 24;
            g64_tile<false, false, bf16>(a.A2b, 512, a.Wet, 512, a.b_e, a.EO,
                                         3000, 3000, nullptr, nullptr, 0, 512,
                                         mt * 64, nt * 128, As, Bs, tid);
        } else {
            int t2 = t - 384;
            int mt = t2 / 5, nt = t2 % 5;
            g64_tile<false, false, bf16>(a.Yv, FP, a.Wb3, FP, a.b_c3, a.G0,
                                         FP, 600, nullptr, nullptr, 0, FP,
                                         mt * 64, nt * 128, As, Bs, tid);
        }
    }
    grid.sync();

    // P1: h1 (80 tiles)
    if (bid < 80) {
        int mt = bid / 5, nt = bid % 5;
        g64_tile<true, true, bf16>(a.G0, FP, a.Wh1t, FP, a.b_h1, a.G1, FP, 600,
                                   a.EO + 0, a.EO + 600, 3000, FP,
                                   mt * 64, nt * 128, As, Bs, tid);
    }
    grid.sync();

    // P2: h2 (80 tiles)
    if (bid < 80) {
        int mt = bid / 5, nt = bid % 5;
        g64_tile<true, true, bf16>(a.G1, FP, a.Wh2t, FP, a.b_h2, a.G2, FP, 600,
                                   a.EO + 1200, a.EO + 1800, 3000, FP,
                                   mt * 64, nt * 128, As, Bs, tid);
    }
    grid.sync();

    // P3: h3 (48 tiles)
    if (bid < 48) {
        int mt = bid / 3, nt = bid % 3;
        g64_tile<false, true, float>(a.G2, FP, a.Wh3t, FP, a.b_h3, a.G3, 300, 300,
                                     a.EO + 2400, a.EO + 2700, 3000, FP,
                                     mt * 64, nt * 128, As, Bs, tid);
    }
    grid.sync();

    // P4: layernorm + text passthrough, rows strided over blocks
    for (int r = bid; r < B; r += 384) {
        float v0 = (tid < 300) ? a.G3[r * 300 + tid] : 0.f;
        float v1 = (tid + 256 < 300) ? a.G3[r * 300 + tid + 256] : 0.f;
        float s = v0 + v1;
        #pragma unroll
        for (int o = 32; o > 0; o >>= 1) s += __shfl_down(s, o, 64);
        if ((tid & 63) == 0) red[tid >> 6] = s;
        __syncthreads();
        if (tid == 0) smu = (red[0] + red[1] + red[2] + red[3]) * (1.f / 300.f);
        __syncthreads();
        float mu = smu;
        float d0 = (tid < 300) ? v0 - mu : 0.f;
        float d1 = (tid + 256 < 300) ? v1 - mu : 0.f;
        s = d0 * d0 + d1 * d1;
        #pragma unroll
        for (int o = 32; o > 0; o >>= 1) s += __shfl_down(s, o, 64);
        if ((tid & 63) == 0) red[tid >> 6] = s;
        __syncthreads();
        if (tid == 0) svar = (red[0] + red[1] + red[2] + red[3]) * (1.f / 300.f);
        __syncthreads();
        float rstd = rsqrtf(svar + 1e-5f);
        if (tid < 300)
            a.out[r * 300 + tid] = d0 * rstd * a.ln_g[tid] + a.ln_b[tid];
        if (tid + 256 < 300)
            a.out[r * 300 + tid + 256] = d1 * rstd * a.ln_g[tid + 256] + a.ln_b[tid + 256];
        float* o2 = a.out + (size_t)B * 300;
        for (int c = tid; c < 300; c += 256)
            o2[(size_t)r * 300 + c] = a.text[(size_t)r * 300 + c];
        __syncthreads();
    }
}

// ---------------------------------------------------------------------------
extern "C" void kernel_launch(void* const* d_in, const int* in_sizes, int n_in,
                              void* d_out, int out_size, void* d_ws, size_t ws_size,
                              hipStream_t stream)
{
    const float* x_in  = (const float*)d_in[0];
    const int*   ei    = (const int*)d_in[1];
    const float* text  = (const float*)d_in[3];
    const float* tst   = (const float*)d_in[4];
    const float* mask  = (const float*)d_in[5];
    const float* W_tr  = (const float*)d_in[6];
    const float* b_tr  = (const float*)d_in[7];
    const float* W_c1  = (const float*)d_in[8];
    const float* b_c1  = (const float*)d_in[9];
    const float* W_c2  = (const float*)d_in[10];
    const float* b_c2  = (const float*)d_in[11];
    const float* W_c3  = (const float*)d_in[12];
    const float* b_c3  = (const float*)d_in[13];
    const float* W_h1  = (const float*)d_in[14];
    const float* b_h1  = (const float*)d_in[15];
    const float* W_h2  = (const float*)d_in[16];
    const float* b_h2  = (const float*)d_in[17];
    const float* W_h3  = (const float*)d_in[18];
    const float* b_h3  = (const float*)d_in[19];
    const float* ln_g  = (const float*)d_in[20];
    const float* ln_b  = (const float*)d_in[21];
    const float* W_t1  = (const float*)d_in[22];
    const float* b_t1  = (const float*)d_in[23];
    const float* W_t2  = (const float*)d_in[24];
    const float* b_t2  = (const float*)d_in[25];
    const float* W_e   = (const float*)d_in[26];
    const float* b_e   = (const float*)d_in[27];

    // workspace carve (256B aligned) — ~155 MB
    char* w = (char*)d_ws;
    size_t off = 0;
    auto carve = [&](size_t bytes) {
        void* p = w + off;
        off += (bytes + 255) & ~(size_t)255;
        return p;
    };
    bf16*  PX0    = (bf16*) carve((size_t)BN * KP1 * 2);     // 42 MB
    bf16*  X1     = (bf16*) carve((size_t)BN * FP * 2);      // 79.7 MB
    bf16*  Wb1    = (bf16*) carve((size_t)640 * KP1 * 2);
    bf16*  Wb2    = (bf16*) carve((size_t)640 * FP * 2);
    bf16*  Wb3    = (bf16*) carve((size_t)640 * FP * 2);
    bf16*  Wt1t   = (bf16*) carve((size_t)512 * 128 * 2);
    bf16*  Wt2t   = (bf16*) carve((size_t)512 * 512 * 2);
    bf16*  Wet    = (bf16*) carve((size_t)3072 * 512 * 2);
    bf16*  Wh1t   = (bf16*) carve((size_t)640 * FP * 2);
    bf16*  Wh2t   = (bf16*) carve((size_t)640 * FP * 2);
    bf16*  Wh3t   = (bf16*) carve((size_t)384 * FP * 2);
    bf16*  TE     = (bf16*) carve((size_t)B * 128 * 2);
    bf16*  A1b    = (bf16*) carve((size_t)B * 512 * 2);
    bf16*  A2b    = (bf16*) carve((size_t)B * 512 * 2);
    bf16*  EO     = (bf16*) carve((size_t)B * 3000 * 2);
    bf16*  Yv     = (bf16*) carve((size_t)B * FP * 2);
    bf16*  G0     = (bf16*) carve((size_t)B * FP * 2);
    bf16*  G1     = (bf16*) carve((size_t)B * FP * 2);
    bf16*  G2     = (bf16*) carve((size_t)B * FP * 2);
    float* G3     = (float*)carve((size_t)B * 300 * 4);
    bf16*  Pmg    = (bf16*) carve((size_t)512 * 128 * PMS * 2);  // 10.5 MB
    float* qv     = (float*)carve((size_t)BN * 4);
    (void)ws_size; (void)in_sizes; (void)n_in; (void)out_size;

    float* out = (float*)d_out;

    // --- dispatch 1: prep_a = {Wc1^T, Wt1^T, TE, PX0} ---
    PrepAArgs pp;
    pp.j[0] = { W_c1, Wb1, 300, 600, KP1, 640, 0 };    // 5*10 = 50 blocks
    pp.j[1] = { W_t1, Wt1t, 128, 512, 128, 512, 50 };  // 2*8  = 16 blocks
    pp.nwt = 66;
    pp.te0 = 66;
    pp.ei = ei; pp.ts = tst;
    pp.xin = x_in; pp.Wtr = W_tr; pp.btr = b_tr; pp.mask = mask;
    pp.TE = TE; pp.PX0 = PX0;
    prep_a<<<66 + 512 + B, 256, 0, stream>>>(pp);

    // --- dispatch 2: conv1 GEMM + guests {t1, 7 transposes, pair-prep} ---
    Conv1Args c1;
    c1.A = PX0; c1.Bt = Wb1; c1.bias = b_c1; c1.X1 = X1;
    c1.TE = TE; c1.Wt1t = Wt1t; c1.b_t1 = b_t1; c1.A1b = A1b;
    // guest transposes (blk0 within wt region)
    c1.wj[0] = { W_c2, Wb2,  600, 600,  FP,  640,  0   };  // 10*10 = 100
    c1.wj[1] = { W_c3, Wb3,  600, 600,  FP,  640,  100 };  // 100
    c1.wj[2] = { W_t2, Wt2t, 512, 512,  512, 512,  200 };  // 8*8 = 64
    c1.wj[3] = { W_e,  Wet,  512, 3000, 512, 3072, 264 };  // 8*48 = 384
    c1.wj[4] = { W_h1, Wh1t, 600, 600,  FP,  640,  648 };  // 100
    c1.wj[5] = { W_h2, Wh2t, 600, 600,  FP,  640,  748 };  // 100
    c1.wj[6] = { W_h3, Wh3t, 600, 300,  FP,  384,  848 };  // 10*6 = 60 -> 908
    c1.ei = ei; c1.Pmg = Pmg; c1.qv = qv;
    c1.t1_end = 64;
    c1.wt_end = 64 + 908;
    conv1_gemm<<<NCONV + 64 + 908 + B, 256, 0, stream>>>(c1);

    // --- dispatch 3: conv2+conv3+pool (+hidden t2) ---
    conv_fused_q<<<NCONV + 64, 256, 0, stream>>>(
        X1, FP, FP, Wb2, FP, Pmg, b_c2, qv, Yv,
        A1b, 512, Wt2t, 512, b_t2, A2b, 512, 512, 512, 4);

    // --- dispatch 4: cooperative tail {EO||G0 -> h1 -> h2 -> h3 -> ln+copy} ---
    TailArgs ta;
    ta.A2b = A2b; ta.Wet = Wet; ta.b_e = b_e; ta.EO = EO;
    ta.Yv = Yv; ta.Wb3 = Wb3; ta.b_c3 = b_c3; ta.G0 = G0;
    ta.Wh1t = Wh1t; ta.b_h1 = b_h1; ta.G1 = G1;
    ta.Wh2t = Wh2t; ta.b_h2 = b_h2; ta.G2 = G2;
    ta.Wh3t = Wh3t; ta.b_h3 = b_h3; ta.G3 = G3;
    ta.ln_g = ln_g; ta.ln_b = ln_b; ta.text = text; ta.out = out;
    void* kargs[] = { (void*)&ta };
    hipLaunchCooperativeKernel((void*)k_tail, dim3(384), dim3(256),
                               kargs, 0, stream);
}

// Round 12
// 525.128 us; speedup vs baseline: 1.1413x; 1.1413x over previous
//
#include <hip/hip_runtime.h>
#include <hip/hip_bf16.h>
#include <cstdint>
#include <cstddef>

// Problem constants
static constexpr int B   = 1024;
static constexpr int N   = 64;
static constexpr int BN  = B * N;      // 65536 nodes
static constexpr int EPG = 192;
static constexpr int E   = B * EPG;    // 196608 edges
static constexpr int FP  = 608;        // padded feature dim (mult of 32)
static constexpr int KP1 = 320;        // conv1 K (PX0 cols, padded)
static constexpr int PMS = 80;         // Pm row stride (bf16)
static constexpr int NCONV = 2560;     // conv blocks per conv dispatch

typedef __hip_bfloat16 bf16;
typedef __bf16 bf16x8 __attribute__((ext_vector_type(8)));
typedef __bf16 bf16x4 __attribute__((ext_vector_type(4)));
typedef float  f32x4  __attribute__((ext_vector_type(4)));

__device__ __forceinline__ void storeC(float* p, float v) { *p = v; }
__device__ __forceinline__ void storeC(bf16* p, float v) { *p = __float2bfloat16(v); }

// async global->LDS, 16B per lane; LDS dest is wave-uniform base + lane*16
__device__ __forceinline__ void llds16(const void* g, void* l) {
    __builtin_amdgcn_global_load_lds(
        (const __attribute__((address_space(1))) unsigned int*)g,
        (__attribute__((address_space(3))) unsigned int*)l,
        16, 0, 0);
}

// ===========================================================================
// 64x128 MFMA GEMM tile body: C[64 x 128 at (m0,n0)] = A @ Bt^T (+bias)(relu)
// (film).  4 waves each 64x32.  As: 4KB, Bs: 8KB.
// NOTE: contains __syncthreads(); when called from multi-group blocks, every
// group must call with the same K so barrier counts match.
// ===========================================================================
template<bool RELU, bool FILM, typename CT>
__device__ __forceinline__ void g64_tile(
    const bf16* __restrict__ A, int lda,
    const bf16* __restrict__ Bt, int ldb,
    const float* __restrict__ bias,
    CT* __restrict__ C, int ldc, int Ncap,
    const bf16* __restrict__ fS, const bf16* __restrict__ fT, int fstride,
    int K, int m0, int n0, __bf16* As, __bf16* Bs, int tid)
{
    const int lane = tid & 63;
    const int w    = tid >> 6;
    const int wn   = w * 32;
    const int l15  = lane & 15;
    const int lhi  = lane >> 4;

    f32x4 acc[4][2] = {};

    for (int k0 = 0; k0 < K; k0 += 32) {
        {   // A tile: 256 chunks of 16B
            int row = tid >> 2, kc = tid & 3;
            char* la = (char*)As + (size_t)(w * 64) * 16;
            llds16(A + (size_t)(m0 + row) * lda + k0 + kc * 8, la);
        }
        #pragma unroll
        for (int t = 0; t < 2; ++t) {   // B tile: 512 chunks
            int ci  = t * 256 + tid;
            int row = ci >> 2, kc = ci & 3;
            char* lb = (char*)Bs + (size_t)(t * 256 + w * 64) * 16;
            llds16(Bt + (size_t)(n0 + row) * ldb + k0 + kc * 8, lb);
        }
        asm volatile("s_waitcnt vmcnt(0)" ::: "memory");
        __syncthreads();

        bf16x8 af[4], bg[2];
        #pragma unroll
        for (int i = 0; i < 4; ++i)
            af[i] = *(bf16x8*)(As + (i * 16 + l15) * 32 + lhi * 8);
        #pragma unroll
        for (int j = 0; j < 2; ++j)
            bg[j] = *(bf16x8*)(Bs + (wn + j * 16 + l15) * 32 + lhi * 8);
        #pragma unroll
        for (int i = 0; i < 4; ++i)
            #pragma unroll
            for (int j = 0; j < 2; ++j)
                acc[i][j] = __builtin_amdgcn_mfma_f32_16x16x32_bf16(
                    af[i], bg[j], acc[i][j], 0, 0, 0);
        __syncthreads();
    }

    #pragma unroll
    for (int i = 0; i < 4; ++i) {
        #pragma unroll
        for (int j = 0; j < 2; ++j) {
            int col = n0 + wn + j * 16 + l15;
            if (col < Ncap) {
                float bv = bias ? bias[col] : 0.f;
                #pragma unroll
                for (int e = 0; e < 4; ++e) {
                    int row = m0 + i * 16 + lhi * 4 + e;
                    float v = acc[i][j][e] + bv;
                    if (RELU) v = fmaxf(v, 0.f);
                    if (FILM) {
                        float sv = __bfloat162float(fS[(size_t)row * fstride + col]);
                        float tv = __bfloat162float(fT[(size_t)row * fstride + col]);
                        v = v * (1.f + sv) + tv;
                    }
                    storeC(&C[(size_t)row * ldc + col], v);
                }
            }
        }
    }
}

// noinline guest wrapper: keeps guest register usage from inflating host VGPRs
__device__ __attribute__((noinline)) void guest_g64(
    const bf16* gA, int glda, const bf16* gBt, int gldb,
    const float* gbias, bf16* gC, int gldc, int gNcap, int gK, int gnt,
    int t, char* lds, int tid)
{
    int mt2 = t / gnt, nt2 = t % gnt;
    g64_tile<true, false, bf16>(gA, glda, gBt, gldb, gbias, gC, gldc, gNcap,
                                nullptr, nullptr, 0, gK, mt2 * 64, nt2 * 128,
                                (__bf16*)lds, (__bf16*)(lds + 4096), tid);
}

// two independent small GEMMs in one dispatch: EO (384 blocks) + G0 (80)
__global__ __launch_bounds__(256) void k_two_gemms(
    const bf16* __restrict__ A2b, const bf16* __restrict__ Wet,
    const float* __restrict__ b_e, bf16* __restrict__ EO,
    const bf16* __restrict__ Yv, const bf16* __restrict__ Wb3,
    const float* __restrict__ b_c3, bf16* __restrict__ G0)
{
    __shared__ __align__(16) __bf16 As[64 * 32];
    __shared__ __align__(16) __bf16 Bs[128 * 32];
    int bid = blockIdx.x;
    if (bid < 384) {
        int mt = bid / 24, nt = bid % 24;
        g64_tile<false, false, bf16>(A2b, 512, Wet, 512, b_e, EO, 3000, 3000,
                                     nullptr, nullptr, 0, 512,
                                     mt * 64, nt * 128, As, Bs, threadIdx.x);
    } else {
        int t = bid - 384;
        int mt = t / 5, nt = t % 5;
        g64_tile<false, false, bf16>(Yv, FP, Wb3, FP, b_c3, G0, FP, 600,
                                     nullptr, nullptr, 0, FP,
                                     mt * 64, nt * 128, As, Bs, threadIdx.x);
    }
}

// ===========================================================================
// Fused h-MLP tail: one block owns 64 rows; h1(5 tiles) -> h2(5) -> h3(3) ->
// LN + text copy.  1024 threads = 4 independent 256-thread g64 groups; tiles
// beyond count run as dummies (Ncap=0) so block-wide barriers stay matched.
// NO grid sync (R11 lesson: grid.sync costs ~60us on 8-XCD MI355X).
// ===========================================================================
struct HmlpArgs {
    const bf16* G0; const bf16* Wh1t; const float* b_h1; bf16* G1;
    const bf16* Wh2t; const float* b_h2; bf16* G2;
    const bf16* Wh3t; const float* b_h3; float* G3;
    const bf16* EO;
    const float* ln_g; const float* ln_b; const float* text; float* out;
};

__global__ __launch_bounds__(1024) void k_hmlp(HmlpArgs a)
{
    __shared__ __align__(16) char lds[4][12288];   // 48 KB
    const int tid  = threadIdx.x;
    const int grp  = tid >> 8;          // 0..3
    const int ltid = tid & 255;
    const int m0   = blockIdx.x * 64;
    __bf16* As = (__bf16*)lds[grp];
    __bf16* Bs = (__bf16*)(lds[grp] + 4096);

    // h1: G1 = film(relu(G0 @ Wh1t^T + b_h1)); 5 tiles over 4 groups, 2 rounds
    #pragma unroll
    for (int rd = 0; rd < 2; ++rd) {
        int t   = rd * 4 + grp;
        int n0  = (t < 5) ? t * 128 : 512;
        int cap = (t < 5) ? 600 : 0;
        g64_tile<true, true, bf16>(a.G0, FP, a.Wh1t, FP, a.b_h1, a.G1, FP, cap,
                                   a.EO + 0, a.EO + 600, 3000, FP,
                                   m0, n0, As, Bs, ltid);
    }
    asm volatile("s_waitcnt vmcnt(0)" ::: "memory");
    __syncthreads();

    // h2
    #pragma unroll
    for (int rd = 0; rd < 2; ++rd) {
        int t   = rd * 4 + grp;
        int n0  = (t < 5) ? t * 128 : 512;
        int cap = (t < 5) ? 600 : 0;
        g64_tile<true, true, bf16>(a.G1, FP, a.Wh2t, FP, a.b_h2, a.G2, FP, cap,
                                   a.EO + 1200, a.EO + 1800, 3000, FP,
                                   m0, n0, As, Bs, ltid);
    }
    asm volatile("s_waitcnt vmcnt(0)" ::: "memory");
    __syncthreads();

    // h3: 3 tiles, 1 round (group 3 dummy)
    {
        int t   = (grp < 3) ? grp : 2;
        int cap = (grp < 3) ? 300 : 0;
        g64_tile<false, true, float>(a.G2, FP, a.Wh3t, FP, a.b_h3, a.G3, 300, cap,
                                     a.EO + 2400, a.EO + 2700, 3000, FP,
                                     m0, t * 128, As, Bs, ltid);
    }
    asm volatile("s_waitcnt vmcnt(0)" ::: "memory");
    __syncthreads();

    // LN (+affine): 16 waves, each wave handles 4 rows, wave-level reduction
    const int wid  = tid >> 6;
    const int lane = tid & 63;
    #pragma unroll
    for (int q = 0; q < 4; ++q) {
        int r = m0 + wid * 4 + q;
        float v[5];
        float s = 0.f;
        #pragma unroll
        for (int k = 0; k < 5; ++k) {
            int c = lane + 64 * k;
            v[k] = (c < 300) ? a.G3[(size_t)r * 300 + c] : 0.f;
            s += v[k];
        }
        #pragma unroll
        for (int o = 32; o > 0; o >>= 1) s += __shfl_down(s, o, 64);
        float mu = __shfl(s, 0, 64) * (1.f / 300.f);
        float s2 = 0.f;
        #pragma unroll
        for (int k = 0; k < 5; ++k) {
            int c = lane + 64 * k;
            float d = (c < 300) ? v[k] - mu : 0.f;
            v[k] = d;
            s2 += d * d;
        }
        #pragma unroll
        for (int o = 32; o > 0; o >>= 1) s2 += __shfl_down(s2, o, 64);
        float rstd = rsqrtf(__shfl(s2, 0, 64) * (1.f / 300.f) + 1e-5f);
        #pragma unroll
        for (int k = 0; k < 5; ++k) {
            int c = lane + 64 * k;
            if (c < 300)
                a.out[(size_t)r * 300 + c] = v[k] * rstd * a.ln_g[c] + a.ln_b[c];
        }
    }
    // text passthrough for this block's 64 rows
    float* o2 = a.out + (size_t)B * 300;
    for (int idx = tid; idx < 64 * 300; idx += 1024) {
        int rr = idx / 300, cc = idx - rr * 300;
        o2[(size_t)(m0 + rr) * 300 + cc] = a.text[(size_t)(m0 + rr) * 300 + cc];
    }
}

// ===========================================================================
// conv1 as a PLAIN GEMM (aggregation pre-commuted into PX0):
// X1 = relu(PX0 @ Wb1^T + b_c1).  128x128 tiles, XCD-swizzled. + hidden t1.
// ===========================================================================
__global__ __launch_bounds__(256) void conv1_gemm(
    const bf16* __restrict__ A,        // PX0, lda = KP1
    const bf16* __restrict__ Bt,       // Wb1, ldb = KP1
    const float* __restrict__ bias,
    bf16* __restrict__ X1,
    const bf16* __restrict__ gA, int glda,
    const bf16* __restrict__ gBt, int gldb,
    const float* __restrict__ gbias,
    bf16* __restrict__ gC, int gldc, int gNcap, int gK, int gnt)
{
    __shared__ __align__(16) char regA[17408];
    const int tid = threadIdx.x;
    const int bid = blockIdx.x;

    if (bid >= NCONV) {
        guest_g64(gA, glda, gBt, gldb, gbias, gC, gldc, gNcap, gK, gnt,
                  bid - NCONV, regA, tid);
        return;
    }

    __bf16* As = (__bf16*)regA;
    __bf16* Bs = (__bf16*)(regA + 8192);

    const int lane = tid & 63;
    const int w    = tid >> 6;
    const int wm   = (w & 1) * 64;
    const int wn   = (w >> 1) * 64;
    const int l15  = lane & 15;
    const int lhi  = lane >> 4;

    const int lid = bid >> 3;
    const int mt  = (bid & 7) * 64 + lid / 5;
    const int nt  = lid % 5;
    const int m0  = mt * 128;
    const int n0  = nt * 128;

    f32x4 acc[4][4] = {};
    for (int k0 = 0; k0 < KP1; k0 += 32) {
        #pragma unroll
        for (int t = 0; t < 2; ++t) {
            int ci  = t * 256 + w * 64 + lane;
            int row = ci >> 2, kc = ci & 3;
            char* la = (char*)As + (size_t)(t * 256 + w * 64) * 16;
            char* lb = (char*)Bs + (size_t)(t * 256 + w * 64) * 16;
            llds16(A  + (size_t)(m0 + row) * KP1 + k0 + kc * 8, la);
            llds16(Bt + (size_t)(n0 + row) * KP1 + k0 + kc * 8, lb);
        }
        asm volatile("s_waitcnt vmcnt(0)" ::: "memory");
        __syncthreads();

        bf16x8 af[4], bg[4];
        #pragma unroll
        for (int i = 0; i < 4; ++i)
            af[i] = *(bf16x8*)(As + (wm + i * 16 + l15) * 32 + lhi * 8);
        #pragma unroll
        for (int j = 0; j < 4; ++j)
            bg[j] = *(bf16x8*)(Bs + (wn + j * 16 + l15) * 32 + lhi * 8);
        #pragma unroll
        for (int i = 0; i < 4; ++i)
            #pragma unroll
            for (int j = 0; j < 4; ++j)
                acc[i][j] = __builtin_amdgcn_mfma_f32_16x16x32_bf16(
                    af[i], bg[j], acc[i][j], 0, 0, 0);
        __syncthreads();
    }

    #pragma unroll
    for (int i = 0; i < 4; ++i)
        #pragma unroll
        for (int j = 0; j < 4; ++j) {
            int col = n0 + wn + j * 16 + l15;
            if (col < FP) {
                float bv = (col < 600) ? bias[col] : 0.f;
                #pragma unroll
                for (int e = 0; e < 4; ++e) {
                    int row = m0 + wm + i * 16 + lhi * 4 + e;
                    float v = fmaxf(acc[i][j][e] + bv, 0.f);
                    X1[(size_t)row * FP + col] = __float2bfloat16(v);
                }
            }
        }
}

// ===========================================================================
// conv2+conv3+pool fused (+ hidden t2 via noinline guest).  Writes only Y.
// ===========================================================================
__global__ __launch_bounds__(256) void conv_fused_q(
    const bf16* __restrict__ A, int lda, int K,
    const bf16* __restrict__ Bt, int ldb,
    const bf16* __restrict__ Pmg,
    const float* __restrict__ bias,
    const float* __restrict__ qv,
    bf16* __restrict__ Y,
    const bf16* __restrict__ gA, int glda,
    const bf16* __restrict__ gBt, int gldb,
    const float* __restrict__ gbias,
    bf16* __restrict__ gC, int gldc, int gNcap, int gK, int gnt)
{
    __shared__ __align__(16) char regA[17408];
    __shared__ __align__(16) __bf16 Pm[128 * PMS];
    __shared__ float s_q[128];

    const int tid = threadIdx.x;
    const int bid = blockIdx.x;

    if (bid >= NCONV) {
        guest_g64(gA, glda, gBt, gldb, gbias, gC, gldc, gNcap, gK, gnt,
                  bid - NCONV, regA, tid);
        return;
    }

    __bf16* As = (__bf16*)regA;
    __bf16* Bs = (__bf16*)(regA + 8192);
    __bf16* Ts = (__bf16*)regA;

    const int lane = tid & 63;
    const int w    = tid >> 6;
    const int wm   = (w & 1) * 64;
    const int wn   = (w >> 1) * 64;
    const int l15  = lane & 15;
    const int lhi  = lane >> 4;

    const int lid = bid >> 3;
    const int mt  = (bid & 7) * 64 + lid / 5;
    const int nt  = lid % 5;
    const int m0  = mt * 128;
    const int n0  = nt * 128;

    #pragma unroll
    for (int i = 0; i < 5; ++i) {
        int cbase = w * 320 + i * 64;
        llds16(Pmg + (size_t)mt * (128 * PMS) + (size_t)(cbase + lane) * 8,
               (char*)Pm + (size_t)cbase * 16);
    }
    if (tid < 128) s_q[tid] = qv[mt * 128 + tid];

    f32x4 acc[4][4] = {};
    for (int k0 = 0; k0 < K; k0 += 32) {
        #pragma unroll
        for (int t = 0; t < 2; ++t) {
            int ci  = t * 256 + w * 64 + lane;
            int row = ci >> 2, kc = ci & 3;
            char* la = (char*)As + (size_t)(t * 256 + w * 64) * 16;
            char* lb = (char*)Bs + (size_t)(t * 256 + w * 64) * 16;
            llds16(A  + (size_t)(m0 + row) * lda + k0 + kc * 8, la);
            llds16(Bt + (size_t)(n0 + row) * ldb + k0 + kc * 8, lb);
        }
        asm volatile("s_waitcnt vmcnt(0)" ::: "memory");
        __syncthreads();

        bf16x8 af[4], bg[4];
        #pragma unroll
        for (int i = 0; i < 4; ++i)
            af[i] = *(bf16x8*)(As + (wm + i * 16 + l15) * 32 + lhi * 8);
        #pragma unroll
        for (int j = 0; j < 4; ++j)
            bg[j] = *(bf16x8*)(Bs + (wn + j * 16 + l15) * 32 + lhi * 8);
        #pragma unroll
        for (int i = 0; i < 4; ++i)
            #pragma unroll
            for (int j = 0; j < 4; ++j)
                acc[i][j] = __builtin_amdgcn_mfma_f32_16x16x32_bf16(
                    af[i], bg[j], acc[i][j], 0, 0, 0);
        __syncthreads();
    }

    const int g  = w & 1;
    const int nb = w >> 1;
    #pragma unroll
    for (int h = 0; h < 2; ++h) {
        if (wn == h * 64) {
            #pragma unroll
            for (int i = 0; i < 4; ++i)
                #pragma unroll
                for (int j = 0; j < 4; ++j) {
                    int c_local = j * 16 + l15;
                    int rbase   = wm + i * 16 + lhi * 4;
                    bf16x4 pk;
                    #pragma unroll
                    for (int e = 0; e < 4; ++e) pk[e] = (__bf16)acc[i][j][e];
                    *(bf16x4*)(Ts + c_local * 136 + rbase) = pk;
                }
        }
        __syncthreads();

        f32x4 acc2[4][2] = {};
        #pragma unroll
        for (int k0 = 0; k0 < 64; k0 += 32) {
            bf16x8 pa[4], hb[2];
            #pragma unroll
            for (int i = 0; i < 4; ++i)
                pa[i] = *(bf16x8*)(Pm + (g * 64 + i * 16 + l15) * PMS + k0 + lhi * 8);
            #pragma unroll
            for (int j = 0; j < 2; ++j)
                hb[j] = *(bf16x8*)(Ts + (nb * 32 + j * 16 + l15) * 136
                                      + g * 64 + k0 + lhi * 8);
            #pragma unroll
            for (int i = 0; i < 4; ++i)
                #pragma unroll
                for (int j = 0; j < 2; ++j)
                    acc2[i][j] = __builtin_amdgcn_mfma_f32_16x16x32_bf16(
                        pa[i], hb[j], acc2[i][j], 0, 0, 0);
        }
        #pragma unroll
        for (int j = 0; j < 2; ++j) {
            int col = n0 + h * 64 + nb * 32 + j * 16 + l15;
            float bv = (col < 600) ? bias[col] : 0.f;
            float yp = 0.f;
            #pragma unroll
            for (int i = 0; i < 4; ++i)
                #pragma unroll
                for (int e = 0; e < 4; ++e) {
                    float v = fmaxf(acc2[i][j][e] + bv, 0.f);   // relu
                    yp += s_q[g * 64 + i * 16 + lhi * 4 + e] * v;
                }
            yp += __shfl_xor(yp, 16, 64);
            yp += __shfl_xor(yp, 32, 64);
            if (lhi == 0 && col < FP)
                Y[(size_t)(mt * 2 + g) * FP + col] = __float2bfloat16(yp);
        }
        __syncthreads();
    }
}

// ===========================================================================
// Mega prep: [WT transposes | timestep emb | pair prep (Pmg,qv) | PX0 branch]
// ===========================================================================
struct WtJob  { const float* src; bf16* dst; int Ksrc, Nsrc, Kp, Np, blk0; };
struct PrepArgs {
    WtJob j[9];
    int nwt, te0, pp0, xtr0;
    const int*   ei;
    const float* ts;
    const float* xin; const float* Wtr; const float* btr; const float* mask;
    bf16* TE; bf16* Pmg; float* qv; bf16* PX0;
};

__global__ __launch_bounds__(256) void k_prep(PrepArgs a)
{
    __shared__ __align__(16) char sm[35840];
    const int bx  = blockIdx.x;
    const int tid = threadIdx.x;

    if (bx < a.nwt) {
        int ji = 0;
        while (ji < 8 && bx >= a.j[ji + 1].blk0) ++ji;
        WtJob jb = a.j[ji];
        int t  = bx - jb.blk0;
        int kt = (jb.Kp + 63) >> 6;
        int ti = t % kt, tj = t / kt;
        int kg0 = ti * 64, ng0 = tj * 64;
        float (*T)[65] = (float(*)[65])sm;
        #pragma unroll 4
        for (int r = 0; r < 16; ++r) {
            int kl = (tid >> 6) + r * 4, nl = tid & 63;
            int kg = kg0 + kl, ng = ng0 + nl;
            T[kl][nl] = (kg < jb.Ksrc && ng < jb.Nsrc)
                        ? jb.src[(size_t)kg * jb.Nsrc + ng] : 0.f;
        }
        __syncthreads();
        #pragma unroll 4
        for (int r = 0; r < 16; ++r) {
            int nl = (tid >> 6) + r * 4, kl = tid & 63;
            int ng = ng0 + nl, kg = kg0 + kl;
            if (ng < jb.Np && kg < jb.Kp)
                jb.dst[(size_t)ng * jb.Kp + kg] = __float2bfloat16(T[kl][nl]);
        }
    } else if (bx < a.pp0) {
        int idx = (bx - a.te0) * 256 + tid;
        int b = idx >> 7, jj = idx & 127;
        float tt = a.ts[b];
        int h = jj & 63;
        float freq = expf(-9.210340371976184f * (float)h / 64.f);  // ln(10000)
        float ang = tt * freq;
        a.TE[idx] = __float2bfloat16((jj < 64) ? cosf(ang) : sinf(ang));
    } else if (bx < a.xtr0) {
        // ---------- pair prep: P matrix (bf16, PMS stride) + q vector ----------
        int pr = bx - a.pp0;
        float* Pf   = (float*)sm;
        int*   cnt  = (int*)(sm + 32768);
        float* sQ   = (float*)(sm + 33280);
        float* sI   = (float*)(sm + 33792);
        float* sIvd = (float*)(sm + 34304);

        for (int idx = tid; idx < 8192; idx += 256) Pf[idx] = 0.f;
        if (tid < 128) cnt[tid] = 0;
        __syncthreads();
        for (int e = tid; e < 2 * EPG; e += 256) {
            int g  = (e >= EPG);
            int eg = (2 * pr + g) * EPG + (e - g * EPG);
            int ld = (a.ei[E + eg] & 63) + g * 64;
            atomicAdd(&cnt[ld], 1);
        }
        __syncthreads();
        if (tid < 128) {
            float d = (float)cnt[tid] + 1.0f;
            float iv = 1.f / d;
            sIvd[tid] = iv;
            sI[tid]   = rsqrtf(d);
            sQ[tid]   = iv;
        }
        __syncthreads();
        for (int e = tid; e < 2 * EPG; e += 256) {
            int g   = (e >= EPG);
            int eg  = (2 * pr + g) * EPG + (e - g * EPG);
            int lsl = a.ei[eg] & 63;
            int ldl = a.ei[E + eg] & 63;
            float cf = sI[g * 64 + lsl] * sI[g * 64 + ldl];
            atomicAdd(&Pf[(g * 64 + ldl) * 64 + lsl], cf);
            atomicAdd(&sQ[g * 64 + lsl], cf);
        }
        __syncthreads();
        if (tid < 128) {
            Pf[tid * 64 + (tid & 63)] += sIvd[tid];
            a.qv[pr * 128 + tid] = sQ[tid] * (1.f / 64.f);
        }
        __syncthreads();
        for (int idx = tid; idx < 128 * PMS; idx += 256) {
            int r = idx / PMS, k = idx - r * PMS;
            float v = (k < 64) ? Pf[r * 64 + k] : 0.f;
            a.Pmg[(size_t)pr * (128 * PMS) + idx] = __float2bfloat16(v);
        }
    } else {
        // ---------- PX0 branch (per graph): PX0 = xa@Wtr + ba*b^T ----------
        int g = bx - a.xtr0;
        float* Pf  = (float*)sm;                 // 64*64 fp32; Ws overlays later
        float* Ws  = (float*)sm;                 // 19*304 fp32
        float* xm  = (float*)(sm + 23104);       // 64*20 (col 19 = mask)
        float* xa  = (float*)(sm + 28224);       // 64*20 (col 19 = ba)
        float* isqv= (float*)(sm + 33344);
        float* ivdv= (float*)(sm + 33600);
        int*   cnt = (int*)  (sm + 33856);
        float* sb  = (float*)(sm + 34112);       // 304

        for (int idx = tid; idx < 4096; idx += 256) Pf[idx] = 0.f;
        if (tid < 64) cnt[tid] = 0;
        __syncthreads();
        if (tid < EPG) atomicAdd(&cnt[a.ei[E + g * EPG + tid] & 63], 1);
        __syncthreads();
        if (tid < 64) {
            float d = (float)cnt[tid] + 1.0f;
            ivdv[tid] = 1.f / d;
            isqv[tid] = rsqrtf(d);
        }
        __syncthreads();
        if (tid < EPG) {
            int ls = a.ei[g * EPG + tid] & 63;
            int ld = a.ei[E + g * EPG + tid] & 63;
            atomicAdd(&Pf[ld * 64 + ls], isqv[ls] * isqv[ld]);
        }
        for (int idx = tid; idx < 64 * 20; idx += 256) {
            int n = idx / 20, j = idx - n * 20;
            float mv = a.mask[g * 64 + n];
            xm[idx] = (j < 19) ? mv * a.xin[(size_t)(g * 64 + n) * 19 + j] : mv;
        }
        __syncthreads();
        if (tid < 64) Pf[tid * 64 + tid] += ivdv[tid];
        __syncthreads();
        for (int idx = tid; idx < 64 * 20; idx += 256) {
            int r = idx / 20, j = idx - r * 20;
            float s = 0.f;
            #pragma unroll 8
            for (int s2 = 0; s2 < 64; ++s2)
                s += Pf[r * 64 + s2] * xm[s2 * 20 + j];
            xa[idx] = s;
        }
        __syncthreads();
        for (int idx = tid; idx < 19 * 304; idx += 256) {
            int k = idx / 304, c = idx - k * 304;
            Ws[idx] = (c < 300) ? a.Wtr[k * 300 + c] : 0.f;
        }
        for (int c = tid; c < 304; c += 256)
            sb[c] = (c < 300) ? a.btr[c] : 0.f;
        __syncthreads();
        int n  = tid >> 2;
        int c0 = tid & 3;
        float ba = xa[n * 20 + 19];
        for (int c = c0; c < 304; c += 4) {
            float acc = ba * sb[c];
            #pragma unroll
            for (int k = 0; k < 19; ++k)
                acc += xa[n * 20 + k] * Ws[k * 304 + c];
            a.PX0[(size_t)(g * 64 + n) * KP1 + c] = __float2bfloat16(acc);
        }
        bf16x8 z = {};
        for (int idx = tid; idx < 64 * 2; idx += 256) {
            int nn = idx >> 1, jv = idx & 1;
            *(bf16x8*)((__bf16*)a.PX0 + (size_t)(g * 64 + nn) * KP1 + 304 + jv * 8) = z;
        }
    }
}

// ---------------------------------------------------------------------------
extern "C" void kernel_launch(void* const* d_in, const int* in_sizes, int n_in,
                              void* d_out, int out_size, void* d_ws, size_t ws_size,
                              hipStream_t stream)
{
    const float* x_in  = (const float*)d_in[0];
    const int*   ei    = (const int*)d_in[1];
    const float* text  = (const float*)d_in[3];
    const float* tst   = (const float*)d_in[4];
    const float* mask  = (const float*)d_in[5];
    const float* W_tr  = (const float*)d_in[6];
    const float* b_tr  = (const float*)d_in[7];
    const float* W_c1  = (const float*)d_in[8];
    const float* b_c1  = (const float*)d_in[9];
    const float* W_c2  = (const float*)d_in[10];
    const float* b_c2  = (const float*)d_in[11];
    const float* W_c3  = (const float*)d_in[12];
    const float* b_c3  = (const float*)d_in[13];
    const float* W_h1  = (const float*)d_in[14];
    const float* b_h1  = (const float*)d_in[15];
    const float* W_h2  = (const float*)d_in[16];
    const float* b_h2  = (const float*)d_in[17];
    const float* W_h3  = (const float*)d_in[18];
    const float* b_h3  = (const float*)d_in[19];
    const float* ln_g  = (const float*)d_in[20];
    const float* ln_b  = (const float*)d_in[21];
    const float* W_t1  = (const float*)d_in[22];
    const float* b_t1  = (const float*)d_in[23];
    const float* W_t2  = (const float*)d_in[24];
    const float* b_t2  = (const float*)d_in[25];
    const float* W_e   = (const float*)d_in[26];
    const float* b_e   = (const float*)d_in[27];

    // workspace carve (256B aligned) — ~155 MB
    char* w = (char*)d_ws;
    size_t off = 0;
    auto carve = [&](size_t bytes) {
        void* p = w + off;
        off += (bytes + 255) & ~(size_t)255;
        return p;
    };
    bf16*  PX0    = (bf16*) carve((size_t)BN * KP1 * 2);     // 42 MB
    bf16*  X1     = (bf16*) carve((size_t)BN * FP * 2);      // 79.7 MB
    bf16*  Wb1    = (bf16*) carve((size_t)640 * KP1 * 2);
    bf16*  Wb2    = (bf16*) carve((size_t)640 * FP * 2);
    bf16*  Wb3    = (bf16*) carve((size_t)640 * FP * 2);
    bf16*  Wt1t   = (bf16*) carve((size_t)512 * 128 * 2);
    bf16*  Wt2t   = (bf16*) carve((size_t)512 * 512 * 2);
    bf16*  Wet    = (bf16*) carve((size_t)3072 * 512 * 2);
    bf16*  Wh1t   = (bf16*) carve((size_t)640 * FP * 2);
    bf16*  Wh2t   = (bf16*) carve((size_t)640 * FP * 2);
    bf16*  Wh3t   = (bf16*) carve((size_t)384 * FP * 2);
    bf16*  TE     = (bf16*) carve((size_t)B * 128 * 2);
    bf16*  A1b    = (bf16*) carve((size_t)B * 512 * 2);
    bf16*  A2b    = (bf16*) carve((size_t)B * 512 * 2);
    bf16*  EO     = (bf16*) carve((size_t)B * 3000 * 2);
    bf16*  Yv     = (bf16*) carve((size_t)B * FP * 2);
    bf16*  G0     = (bf16*) carve((size_t)B * FP * 2);
    bf16*  G1     = (bf16*) carve((size_t)B * FP * 2);
    bf16*  G2     = (bf16*) carve((size_t)B * FP * 2);
    float* G3     = (float*)carve((size_t)B * 300 * 4);
    bf16*  Pmg    = (bf16*) carve((size_t)512 * 128 * PMS * 2);  // 10.5 MB
    float* qv     = (float*)carve((size_t)BN * 4);
    (void)ws_size; (void)in_sizes; (void)n_in; (void)out_size;

    float* out = (float*)d_out;

    // --- dispatch 1: mega prep ---
    PrepArgs pa;
    struct JD { const float* s; bf16* d; int Ks, Ns, Kp, Np; };
    JD jd[9] = {
        { W_c1, Wb1,  300, 600,  KP1, 640 },
        { W_c2, Wb2,  600, 600,  FP,  640 },
        { W_c3, Wb3,  600, 600,  FP,  640 },
        { W_t1, Wt1t, 128, 512,  128, 512 },
        { W_t2, Wt2t, 512, 512,  512, 512 },
        { W_e,  Wet,  512, 3000, 512, 3072 },
        { W_h1, Wh1t, 600, 600,  FP,  640 },
        { W_h2, Wh2t, 600, 600,  FP,  640 },
        { W_h3, Wh3t, 600, 300,  FP,  384 },
    };
    int cum = 0;
    for (int i = 0; i < 9; ++i) {
        int kt = (jd[i].Kp + 63) >> 6, nt = (jd[i].Np + 63) >> 6;
        pa.j[i] = { jd[i].s, jd[i].d, jd[i].Ks, jd[i].Ns, jd[i].Kp, jd[i].Np, cum };
        cum += kt * nt;
    }
    pa.nwt  = cum;
    pa.te0  = cum;       cum += (B * 128) / 256;
    pa.pp0  = cum;       cum += B / 2;
    pa.xtr0 = cum;       cum += B;
    pa.ei = ei; pa.ts = tst;
    pa.xin = x_in; pa.Wtr = W_tr; pa.btr = b_tr; pa.mask = mask;
    pa.TE = TE; pa.Pmg = Pmg; pa.qv = qv; pa.PX0 = PX0;
    k_prep<<<cum, 256, 0, stream>>>(pa);

    // --- dispatch 2: conv1 plain GEMM (+hidden t1) ---
    conv1_gemm<<<NCONV + 64, 256, 0, stream>>>(
        PX0, Wb1, b_c1, X1,
        TE, 128, Wt1t, 128, b_t1, A1b, 512, 512, 128, 4);

    // --- dispatch 3: conv2+conv3+pool (+hidden t2) ---
    conv_fused_q<<<NCONV + 64, 256, 0, stream>>>(
        X1, FP, FP, Wb2, FP, Pmg, b_c2, qv, Yv,
        A1b, 512, Wt2t, 512, b_t2, A2b, 512, 512, 512, 4);

    // --- dispatch 4: EO || G0 ---
    k_two_gemms<<<464, 256, 0, stream>>>(A2b, Wet, b_e, EO, Yv, Wb3, b_c3, G0);

    // --- dispatch 5: fused h-MLP tail (block-local chain, no grid sync) ---
    HmlpArgs hm;
    hm.G0 = G0; hm.Wh1t = Wh1t; hm.b_h1 = b_h1; hm.G1 = G1;
    hm.Wh2t = Wh2t; hm.b_h2 = b_h2; hm.G2 = G2;
    hm.Wh3t = Wh3t; hm.b_h3 = b_h3; hm.G3 = G3;
    hm.EO = EO; hm.ln_g = ln_g; hm.ln_b = ln_b; hm.text = text; hm.out = out;
    k_hmlp<<<16, 1024, 0, stream>>>(hm);
}

// Round 13
// 370.031 us; speedup vs baseline: 1.6197x; 1.4191x over previous
//
#include <hip/hip_runtime.h>
#include <hip/hip_bf16.h>
#include <cstdint>
#include <cstddef>

// Problem constants
static constexpr int B   = 1024;
static constexpr int N   = 64;
static constexpr int BN  = B * N;      // 65536 nodes
static constexpr int EPG = 192;
static constexpr int E   = B * EPG;    // 196608 edges
static constexpr int FP  = 608;        // padded feature dim (mult of 32)
static constexpr int KP1 = 320;        // conv1 K (PX0 cols, padded)
static constexpr int PMS = 80;         // Pm row stride (bf16)
static constexpr int NCONV = 2560;     // conv blocks per conv dispatch

typedef __hip_bfloat16 bf16;
typedef __bf16 bf16x8 __attribute__((ext_vector_type(8)));
typedef __bf16 bf16x4 __attribute__((ext_vector_type(4)));
typedef float  f32x4  __attribute__((ext_vector_type(4)));

__device__ __forceinline__ void storeC(float* p, float v) { *p = v; }
__device__ __forceinline__ void storeC(bf16* p, float v) { *p = __float2bfloat16(v); }

// async global->LDS, 16B per lane; LDS dest is wave-uniform base + lane*16
__device__ __forceinline__ void llds16(const void* g, void* l) {
    __builtin_amdgcn_global_load_lds(
        (const __attribute__((address_space(1))) unsigned int*)g,
        (__attribute__((address_space(3))) unsigned int*)l,
        16, 0, 0);
}

// ===========================================================================
// 64x128 MFMA GEMM tile body: C[64 x 128 at (m0,n0)] = A @ Bt^T (+bias)(relu)
// (film).  4 waves each 64x32.  As: 4KB, Bs: 8KB.
// ===========================================================================
template<bool RELU, bool FILM, typename CT>
__device__ __forceinline__ void g64_tile(
    const bf16* __restrict__ A, int lda,
    const bf16* __restrict__ Bt, int ldb,
    const float* __restrict__ bias,
    CT* __restrict__ C, int ldc, int Ncap,
    const bf16* __restrict__ fS, const bf16* __restrict__ fT, int fstride,
    int K, int m0, int n0, __bf16* As, __bf16* Bs, int tid)
{
    const int lane = tid & 63;
    const int w    = tid >> 6;
    const int wn   = w * 32;
    const int l15  = lane & 15;
    const int lhi  = lane >> 4;

    f32x4 acc[4][2] = {};

    for (int k0 = 0; k0 < K; k0 += 32) {
        {   // A tile: 256 chunks of 16B, one per thread
            int row = tid >> 2, kc = tid & 3;
            char* la = (char*)As + (size_t)(w * 64) * 16;
            llds16(A + (size_t)(m0 + row) * lda + k0 + kc * 8, la);
        }
        #pragma unroll
        for (int t = 0; t < 2; ++t) {   // B tile: 512 chunks
            int ci  = t * 256 + tid;
            int row = ci >> 2, kc = ci & 3;
            char* lb = (char*)Bs + (size_t)(t * 256 + w * 64) * 16;
            llds16(Bt + (size_t)(n0 + row) * ldb + k0 + kc * 8, lb);
        }
        asm volatile("s_waitcnt vmcnt(0)" ::: "memory");
        __syncthreads();

        bf16x8 af[4], bg[2];
        #pragma unroll
        for (int i = 0; i < 4; ++i)
            af[i] = *(bf16x8*)(As + (i * 16 + l15) * 32 + lhi * 8);
        #pragma unroll
        for (int j = 0; j < 2; ++j)
            bg[j] = *(bf16x8*)(Bs + (wn + j * 16 + l15) * 32 + lhi * 8);
        #pragma unroll
        for (int i = 0; i < 4; ++i)
            #pragma unroll
            for (int j = 0; j < 2; ++j)
                acc[i][j] = __builtin_amdgcn_mfma_f32_16x16x32_bf16(
                    af[i], bg[j], acc[i][j], 0, 0, 0);
        __syncthreads();
    }

    #pragma unroll
    for (int i = 0; i < 4; ++i) {
        #pragma unroll
        for (int j = 0; j < 2; ++j) {
            int col = n0 + wn + j * 16 + l15;
            if (col < Ncap) {
                float bv = bias ? bias[col] : 0.f;
                #pragma unroll
                for (int e = 0; e < 4; ++e) {
                    int row = m0 + i * 16 + lhi * 4 + e;
                    float v = acc[i][j][e] + bv;
                    if (RELU) v = fmaxf(v, 0.f);
                    if (FILM) {
                        float sv = __bfloat162float(fS[(size_t)row * fstride + col]);
                        float tv = __bfloat162float(fT[(size_t)row * fstride + col]);
                        v = v * (1.f + sv) + tv;
                    }
                    storeC(&C[(size_t)row * ldc + col], v);
                }
            }
        }
    }
}

// noinline guest wrapper: keeps guest register usage from inflating host VGPRs
__device__ __attribute__((noinline)) void guest_g64(
    const bf16* gA, int glda, const bf16* gBt, int gldb,
    const float* gbias, bf16* gC, int gldc, int gNcap, int gK, int gnt,
    int t, char* lds, int tid)
{
    int mt2 = t / gnt, nt2 = t % gnt;
    g64_tile<true, false, bf16>(gA, glda, gBt, gldb, gbias, gC, gldc, gNcap,
                                nullptr, nullptr, 0, gK, mt2 * 64, nt2 * 128,
                                (__bf16*)lds, (__bf16*)(lds + 4096), tid);
}

// standalone 64-row-tile GEMM (h-layers)
template<bool RELU, bool FILM, typename CT>
__global__ __launch_bounds__(256) void gemm64(
    const bf16* __restrict__ A, int lda,
    const bf16* __restrict__ Bt, int ldb,
    const float* __restrict__ bias,
    CT* __restrict__ C, int ldc, int Ncap,
    const bf16* __restrict__ fS, const bf16* __restrict__ fT, int fstride,
    int K)
{
    __shared__ __align__(16) __bf16 As[64 * 32];
    __shared__ __align__(16) __bf16 Bs[128 * 32];
    g64_tile<RELU, FILM, CT>(A, lda, Bt, ldb, bias, C, ldc, Ncap,
                             fS, fT, fstride, K,
                             blockIdx.x * 64, blockIdx.y * 128, As, Bs,
                             threadIdx.x);
}

// two independent small GEMMs in one dispatch: EO (384 blocks) + G0 (80)
__global__ __launch_bounds__(256) void k_two_gemms(
    const bf16* __restrict__ A2b, const bf16* __restrict__ Wet,
    const float* __restrict__ b_e, bf16* __restrict__ EO,
    const bf16* __restrict__ Yv, const bf16* __restrict__ Wb3,
    const float* __restrict__ b_c3, bf16* __restrict__ G0)
{
    __shared__ __align__(16) __bf16 As[64 * 32];
    __shared__ __align__(16) __bf16 Bs[128 * 32];
    int bid = blockIdx.x;
    if (bid < 384) {
        int mt = bid / 24, nt = bid % 24;
        g64_tile<false, false, bf16>(A2b, 512, Wet, 512, b_e, EO, 3000, 3000,
                                     nullptr, nullptr, 0, 512,
                                     mt * 64, nt * 128, As, Bs, threadIdx.x);
    } else {
        int t = bid - 384;
        int mt = t / 5, nt = t % 5;
        g64_tile<false, false, bf16>(Yv, FP, Wb3, FP, b_c3, G0, FP, 600,
                                     nullptr, nullptr, 0, FP,
                                     mt * 64, nt * 128, As, Bs, threadIdx.x);
    }
}

// ===========================================================================
// conv1 as a PLAIN GEMM (aggregation pre-commuted into PX0):
// X1 = relu(PX0 @ Wb1^T + b_c1).  128x128 tiles, XCD-swizzled. + hidden t1.
// ===========================================================================
__global__ __launch_bounds__(256) void conv1_gemm(
    const bf16* __restrict__ A,        // PX0, lda = KP1
    const bf16* __restrict__ Bt,       // Wb1, ldb = KP1
    const float* __restrict__ bias,
    bf16* __restrict__ X1,
    const bf16* __restrict__ gA, int glda,
    const bf16* __restrict__ gBt, int gldb,
    const float* __restrict__ gbias,
    bf16* __restrict__ gC, int gldc, int gNcap, int gK, int gnt)
{
    __shared__ __align__(16) char regA[17408];
    const int tid = threadIdx.x;
    const int bid = blockIdx.x;

    if (bid >= NCONV) {
        guest_g64(gA, glda, gBt, gldb, gbias, gC, gldc, gNcap, gK, gnt,
                  bid - NCONV, regA, tid);
        return;
    }

    __bf16* As = (__bf16*)regA;
    __bf16* Bs = (__bf16*)(regA + 8192);

    const int lane = tid & 63;
    const int w    = tid >> 6;
    const int wm   = (w & 1) * 64;
    const int wn   = (w >> 1) * 64;
    const int l15  = lane & 15;
    const int lhi  = lane >> 4;

    const int lid = bid >> 3;
    const int mt  = (bid & 7) * 64 + lid / 5;
    const int nt  = lid % 5;
    const int m0  = mt * 128;
    const int n0  = nt * 128;

    f32x4 acc[4][4] = {};
    for (int k0 = 0; k0 < KP1; k0 += 32) {
        #pragma unroll
        for (int t = 0; t < 2; ++t) {
            int ci  = t * 256 + w * 64 + lane;
            int row = ci >> 2, kc = ci & 3;
            char* la = (char*)regA + (size_t)(t * 256 + w * 64) * 16;
            char* lb = (char*)regA + 8192 + (size_t)(t * 256 + w * 64) * 16;
            llds16(A  + (size_t)(m0 + row) * KP1 + k0 + kc * 8, la);
            llds16(Bt + (size_t)(n0 + row) * KP1 + k0 + kc * 8, lb);
        }
        asm volatile("s_waitcnt vmcnt(0)" ::: "memory");
        __syncthreads();

        bf16x8 af[4], bg[4];
        #pragma unroll
        for (int i = 0; i < 4; ++i)
            af[i] = *(bf16x8*)(As + (wm + i * 16 + l15) * 32 + lhi * 8);
        #pragma unroll
        for (int j = 0; j < 4; ++j)
            bg[j] = *(bf16x8*)(Bs + (wn + j * 16 + l15) * 32 + lhi * 8);
        #pragma unroll
        for (int i = 0; i < 4; ++i)
            #pragma unroll
            for (int j = 0; j < 4; ++j)
                acc[i][j] = __builtin_amdgcn_mfma_f32_16x16x32_bf16(
                    af[i], bg[j], acc[i][j], 0, 0, 0);
        __syncthreads();
    }

    #pragma unroll
    for (int i = 0; i < 4; ++i)
        #pragma unroll
        for (int j = 0; j < 4; ++j) {
            int col = n0 + wn + j * 16 + l15;
            if (col < FP) {
                float bv = (col < 600) ? bias[col] : 0.f;
                #pragma unroll
                for (int e = 0; e < 4; ++e) {
                    int row = m0 + wm + i * 16 + lhi * 4 + e;
                    float v = fmaxf(acc[i][j][e] + bv, 0.f);
                    X1[(size_t)row * FP + col] = __float2bfloat16(v);
                }
            }
        }
}

// ===========================================================================
// conv2+conv3+pool fused (+ hidden t2 via noinline guest).  Writes only Y.
// R13 change vs R10: P fragments read DIRECTLY from global (L2-hot Pmg,
// 10.5 MB, XCD-swizzled locality) instead of LDS staging.  LDS 38.4->17.9 KB
// -> ~6 blocks/CU instead of 4.
// ===========================================================================
__global__ __launch_bounds__(256) void conv_fused_q(
    const bf16* __restrict__ A, int lda, int K,
    const bf16* __restrict__ Bt, int ldb,
    const bf16* __restrict__ Pmg,
    const float* __restrict__ bias,
    const float* __restrict__ qv,
    bf16* __restrict__ Y,
    const bf16* __restrict__ gA, int glda,
    const bf16* __restrict__ gBt, int gldb,
    const float* __restrict__ gbias,
    bf16* __restrict__ gC, int gldc, int gNcap, int gK, int gnt)
{
    __shared__ __align__(16) char regA[17408];
    __shared__ float s_q[128];

    const int tid = threadIdx.x;
    const int bid = blockIdx.x;

    if (bid >= NCONV) {
        guest_g64(gA, glda, gBt, gldb, gbias, gC, gldc, gNcap, gK, gnt,
                  bid - NCONV, regA, tid);
        return;
    }

    __bf16* As = (__bf16*)regA;
    __bf16* Bs = (__bf16*)(regA + 8192);
    __bf16* Ts = (__bf16*)regA;

    const int lane = tid & 63;
    const int w    = tid >> 6;
    const int wm   = (w & 1) * 64;
    const int wn   = (w >> 1) * 64;
    const int l15  = lane & 15;
    const int lhi  = lane >> 4;

    const int lid = bid >> 3;
    const int mt  = (bid & 7) * 64 + lid / 5;
    const int nt  = lid % 5;
    const int m0  = mt * 128;
    const int n0  = nt * 128;

    if (tid < 128) s_q[tid] = qv[mt * 128 + tid];

    f32x4 acc[4][4] = {};
    for (int k0 = 0; k0 < K; k0 += 32) {
        #pragma unroll
        for (int t = 0; t < 2; ++t) {
            int ci  = t * 256 + w * 64 + lane;
            int row = ci >> 2, kc = ci & 3;
            char* la = (char*)regA + (size_t)(t * 256 + w * 64) * 16;
            char* lb = (char*)regA + 8192 + (size_t)(t * 256 + w * 64) * 16;
            llds16(A  + (size_t)(m0 + row) * lda + k0 + kc * 8, la);
            llds16(Bt + (size_t)(n0 + row) * ldb + k0 + kc * 8, lb);
        }
        asm volatile("s_waitcnt vmcnt(0)" ::: "memory");
        __syncthreads();

        bf16x8 af[4], bg[4];
        #pragma unroll
        for (int i = 0; i < 4; ++i)
            af[i] = *(bf16x8*)(As + (wm + i * 16 + l15) * 32 + lhi * 8);
        #pragma unroll
        for (int j = 0; j < 4; ++j)
            bg[j] = *(bf16x8*)(Bs + (wn + j * 16 + l15) * 32 + lhi * 8);
        #pragma unroll
        for (int i = 0; i < 4; ++i)
            #pragma unroll
            for (int j = 0; j < 4; ++j)
                acc[i][j] = __builtin_amdgcn_mfma_f32_16x16x32_bf16(
                    af[i], bg[j], acc[i][j], 0, 0, 0);
        __syncthreads();
    }

    const bf16* Pbase = Pmg + (size_t)mt * (128 * PMS);
    const int g  = w & 1;
    const int nb = w >> 1;
    #pragma unroll
    for (int h = 0; h < 2; ++h) {
        if (wn == h * 64) {
            #pragma unroll
            for (int i = 0; i < 4; ++i)
                #pragma unroll
                for (int j = 0; j < 4; ++j) {
                    int c_local = j * 16 + l15;
                    int rbase   = wm + i * 16 + lhi * 4;
                    bf16x4 pk;
                    #pragma unroll
                    for (int e = 0; e < 4; ++e) pk[e] = (__bf16)acc[i][j][e];
                    *(bf16x4*)(Ts + c_local * 136 + rbase) = pk;
                }
        }
        __syncthreads();

        f32x4 acc2[4][2] = {};
        #pragma unroll
        for (int k0 = 0; k0 < 64; k0 += 32) {
            bf16x8 pa[4], hb[2];
            #pragma unroll
            for (int i = 0; i < 4; ++i)
                pa[i] = *(const bf16x8*)((const __bf16*)Pbase
                          + (size_t)(g * 64 + i * 16 + l15) * PMS + k0 + lhi * 8);
            #pragma unroll
            for (int j = 0; j < 2; ++j)
                hb[j] = *(bf16x8*)(Ts + (nb * 32 + j * 16 + l15) * 136
                                      + g * 64 + k0 + lhi * 8);
            #pragma unroll
            for (int i = 0; i < 4; ++i)
                #pragma unroll
                for (int j = 0; j < 2; ++j)
                    acc2[i][j] = __builtin_amdgcn_mfma_f32_16x16x32_bf16(
                        pa[i], hb[j], acc2[i][j], 0, 0, 0);
        }
        #pragma unroll
        for (int j = 0; j < 2; ++j) {
            int col = n0 + h * 64 + nb * 32 + j * 16 + l15;
            float bv = (col < 600) ? bias[col] : 0.f;
            float yp = 0.f;
            #pragma unroll
            for (int i = 0; i < 4; ++i)
                #pragma unroll
                for (int e = 0; e < 4; ++e) {
                    float v = fmaxf(acc2[i][j][e] + bv, 0.f);   // relu
                    yp += s_q[g * 64 + i * 16 + lhi * 4 + e] * v;
                }
            yp += __shfl_xor(yp, 16, 64);
            yp += __shfl_xor(yp, 32, 64);
            if (lhi == 0 && col < FP)
                Y[(size_t)(mt * 2 + g) * FP + col] = __float2bfloat16(yp);
        }
        __syncthreads();
    }
}

// ===========================================================================
// Mega prep: [WT transposes | timestep emb | pair prep (Pmg,qv) | PX0 branch]
// ===========================================================================
struct WtJob  { const float* src; bf16* dst; int Ksrc, Nsrc, Kp, Np, blk0; };
struct PrepArgs {
    WtJob j[9];
    int nwt, te0, pp0, xtr0;
    const int*   ei;
    const float* ts;
    const float* xin; const float* Wtr; const float* btr; const float* mask;
    bf16* TE; bf16* Pmg; float* qv; bf16* PX0;
};

__global__ __launch_bounds__(256) void k_prep(PrepArgs a)
{
    __shared__ __align__(16) char sm[35840];
    const int bx  = blockIdx.x;
    const int tid = threadIdx.x;

    if (bx < a.nwt) {
        int ji = 0;
        while (ji < 8 && bx >= a.j[ji + 1].blk0) ++ji;
        WtJob jb = a.j[ji];
        int t  = bx - jb.blk0;
        int kt = (jb.Kp + 63) >> 6;
        int ti = t % kt, tj = t / kt;
        int kg0 = ti * 64, ng0 = tj * 64;
        float (*T)[65] = (float(*)[65])sm;
        #pragma unroll 4
        for (int r = 0; r < 16; ++r) {
            int kl = (tid >> 6) + r * 4, nl = tid & 63;
            int kg = kg0 + kl, ng = ng0 + nl;
            T[kl][nl] = (kg < jb.Ksrc && ng < jb.Nsrc)
                        ? jb.src[(size_t)kg * jb.Nsrc + ng] : 0.f;
        }
        __syncthreads();
        #pragma unroll 4
        for (int r = 0; r < 16; ++r) {
            int nl = (tid >> 6) + r * 4, kl = tid & 63;
            int ng = ng0 + nl, kg = kg0 + kl;
            if (ng < jb.Np && kg < jb.Kp)
                jb.dst[(size_t)ng * jb.Kp + kg] = __float2bfloat16(T[kl][nl]);
        }
    } else if (bx < a.pp0) {
        int idx = (bx - a.te0) * 256 + tid;
        int b = idx >> 7, jj = idx & 127;
        float tt = a.ts[b];
        int h = jj & 63;
        float freq = expf(-9.210340371976184f * (float)h / 64.f);  // ln(10000)
        float ang = tt * freq;
        a.TE[idx] = __float2bfloat16((jj < 64) ? cosf(ang) : sinf(ang));
    } else if (bx < a.xtr0) {
        // ---------- pair prep: P matrix (bf16, PMS stride) + q vector ----------
        int pr = bx - a.pp0;
        float* Pf   = (float*)sm;
        int*   cnt  = (int*)(sm + 32768);
        float* sQ   = (float*)(sm + 33280);
        float* sI   = (float*)(sm + 33792);
        float* sIvd = (float*)(sm + 34304);

        for (int idx = tid; idx < 8192; idx += 256) Pf[idx] = 0.f;
        if (tid < 128) cnt[tid] = 0;
        __syncthreads();
        for (int e = tid; e < 2 * EPG; e += 256) {
            int g  = (e >= EPG);
            int eg = (2 * pr + g) * EPG + (e - g * EPG);
            int ld = (a.ei[E + eg] & 63) + g * 64;
            atomicAdd(&cnt[ld], 1);
        }
        __syncthreads();
        if (tid < 128) {
            float d = (float)cnt[tid] + 1.0f;
            float iv = 1.f / d;
            sIvd[tid] = iv;
            sI[tid]   = rsqrtf(d);
            sQ[tid]   = iv;
        }
        __syncthreads();
        for (int e = tid; e < 2 * EPG; e += 256) {
            int g   = (e >= EPG);
            int eg  = (2 * pr + g) * EPG + (e - g * EPG);
            int lsl = a.ei[eg] & 63;
            int ldl = a.ei[E + eg] & 63;
            float cf = sI[g * 64 + lsl] * sI[g * 64 + ldl];
            atomicAdd(&Pf[(g * 64 + ldl) * 64 + lsl], cf);
            atomicAdd(&sQ[g * 64 + lsl], cf);
        }
        __syncthreads();
        if (tid < 128) {
            Pf[tid * 64 + (tid & 63)] += sIvd[tid];
            a.qv[pr * 128 + tid] = sQ[tid] * (1.f / 64.f);
        }
        __syncthreads();
        for (int idx = tid; idx < 128 * PMS; idx += 256) {
            int r = idx / PMS, k = idx - r * PMS;
            float v = (k < 64) ? Pf[r * 64 + k] : 0.f;
            a.Pmg[(size_t)pr * (128 * PMS) + idx] = __float2bfloat16(v);
        }
    } else {
        // ---------- PX0 branch (per graph): PX0 = xa@Wtr + ba*b^T ----------
        int g = bx - a.xtr0;
        float* Pf  = (float*)sm;                 // 64*64 fp32; Ws overlays later
        float* Ws  = (float*)sm;                 // 19*304 fp32
        float* xm  = (float*)(sm + 23104);       // 64*20 (col 19 = mask)
        float* xa  = (float*)(sm + 28224);       // 64*20 (col 19 = ba)
        float* isqv= (float*)(sm + 33344);
        float* ivdv= (float*)(sm + 33600);
        int*   cnt = (int*)  (sm + 33856);
        float* sb  = (float*)(sm + 34112);       // 304

        for (int idx = tid; idx < 4096; idx += 256) Pf[idx] = 0.f;
        if (tid < 64) cnt[tid] = 0;
        __syncthreads();
        if (tid < EPG) atomicAdd(&cnt[a.ei[E + g * EPG + tid] & 63], 1);
        __syncthreads();
        if (tid < 64) {
            float d = (float)cnt[tid] + 1.0f;
            ivdv[tid] = 1.f / d;
            isqv[tid] = rsqrtf(d);
        }
        __syncthreads();
        if (tid < EPG) {
            int ls = a.ei[g * EPG + tid] & 63;
            int ld = a.ei[E + g * EPG + tid] & 63;
            atomicAdd(&Pf[ld * 64 + ls], isqv[ls] * isqv[ld]);
        }
        for (int idx = tid; idx < 64 * 20; idx += 256) {
            int n = idx / 20, j = idx - n * 20;
            float mv = a.mask[g * 64 + n];
            xm[idx] = (j < 19) ? mv * a.xin[(size_t)(g * 64 + n) * 19 + j] : mv;
        }
        __syncthreads();
        if (tid < 64) Pf[tid * 64 + tid] += ivdv[tid];
        __syncthreads();
        for (int idx = tid; idx < 64 * 20; idx += 256) {
            int r = idx / 20, j = idx - r * 20;
            float s = 0.f;
            #pragma unroll 8
            for (int s2 = 0; s2 < 64; ++s2)
                s += Pf[r * 64 + s2] * xm[s2 * 20 + j];
            xa[idx] = s;
        }
        __syncthreads();
        for (int idx = tid; idx < 19 * 304; idx += 256) {
            int k = idx / 304, c = idx - k * 304;
            Ws[idx] = (c < 300) ? a.Wtr[k * 300 + c] : 0.f;
        }
        for (int c = tid; c < 304; c += 256)
            sb[c] = (c < 300) ? a.btr[c] : 0.f;
        __syncthreads();
        int n  = tid >> 2;
        int c0 = tid & 3;
        float ba = xa[n * 20 + 19];
        for (int c = c0; c < 304; c += 4) {
            float acc = ba * sb[c];
            #pragma unroll
            for (int k = 0; k < 19; ++k)
                acc += xa[n * 20 + k] * Ws[k * 304 + c];
            a.PX0[(size_t)(g * 64 + n) * KP1 + c] = __float2bfloat16(acc);
        }
        bf16x8 z = {};
        for (int idx = tid; idx < 64 * 2; idx += 256) {
            int nn = idx >> 1, jv = idx & 1;
            *(bf16x8*)((__bf16*)a.PX0 + (size_t)(g * 64 + nn) * KP1 + 304 + jv * 8) = z;
        }
    }
}

// LayerNorm over 300 dims + affine, fp32 out; fused text passthrough copy
__global__ __launch_bounds__(256) void k_ln_copy(const float* __restrict__ G,
                                                 const float* __restrict__ lg,
                                                 const float* __restrict__ lb,
                                                 const float* __restrict__ text,
                                                 float* __restrict__ out)
{
    int r = blockIdx.x;
    int tid = threadIdx.x;
    __shared__ float red[4];
    __shared__ float smu, svar;

    float v0 = (tid < 300) ? G[r * 300 + tid] : 0.f;
    float v1 = (tid + 256 < 300) ? G[r * 300 + tid + 256] : 0.f;
    float s = v0 + v1;
    #pragma unroll
    for (int o = 32; o > 0; o >>= 1) s += __shfl_down(s, o, 64);
    if ((tid & 63) == 0) red[tid >> 6] = s;
    __syncthreads();
    if (tid == 0) smu = (red[0] + red[1] + red[2] + red[3]) * (1.f / 300.f);
    __syncthreads();
    float mu = smu;
    float d0 = (tid < 300) ? v0 - mu : 0.f;
    float d1 = (tid + 256 < 300) ? v1 - mu : 0.f;
    s = d0 * d0 + d1 * d1;
    #pragma unroll
    for (int o = 32; o > 0; o >>= 1) s += __shfl_down(s, o, 64);
    if ((tid & 63) == 0) red[tid >> 6] = s;
    __syncthreads();
    if (tid == 0) svar = (red[0] + red[1] + red[2] + red[3]) * (1.f / 300.f);
    __syncthreads();
    float rstd = rsqrtf(svar + 1e-5f);
    if (tid < 300)
        out[r * 300 + tid] = d0 * rstd * lg[tid] + lb[tid];
    if (tid + 256 < 300)
        out[r * 300 + tid + 256] = d1 * rstd * lg[tid + 256] + lb[tid + 256];
    float* o2 = out + (size_t)B * 300;
    for (int c = tid; c < 300; c += 256)
        o2[(size_t)r * 300 + c] = text[(size_t)r * 300 + c];
}

// ---------------------------------------------------------------------------
extern "C" void kernel_launch(void* const* d_in, const int* in_sizes, int n_in,
                              void* d_out, int out_size, void* d_ws, size_t ws_size,
                              hipStream_t stream)
{
    const float* x_in  = (const float*)d_in[0];
    const int*   ei    = (const int*)d_in[1];
    const float* text  = (const float*)d_in[3];
    const float* tst   = (const float*)d_in[4];
    const float* mask  = (const float*)d_in[5];
    const float* W_tr  = (const float*)d_in[6];
    const float* b_tr  = (const float*)d_in[7];
    const float* W_c1  = (const float*)d_in[8];
    const float* b_c1  = (const float*)d_in[9];
    const float* W_c2  = (const float*)d_in[10];
    const float* b_c2  = (const float*)d_in[11];
    const float* W_c3  = (const float*)d_in[12];
    const float* b_c3  = (const float*)d_in[13];
    const float* W_h1  = (const float*)d_in[14];
    const float* b_h1  = (const float*)d_in[15];
    const float* W_h2  = (const float*)d_in[16];
    const float* b_h2  = (const float*)d_in[17];
    const float* W_h3  = (const float*)d_in[18];
    const float* b_h3  = (const float*)d_in[19];
    const float* ln_g  = (const float*)d_in[20];
    const float* ln_b  = (const float*)d_in[21];
    const float* W_t1  = (const float*)d_in[22];
    const float* b_t1  = (const float*)d_in[23];
    const float* W_t2  = (const float*)d_in[24];
    const float* b_t2  = (const float*)d_in[25];
    const float* W_e   = (const float*)d_in[26];
    const float* b_e   = (const float*)d_in[27];

    // workspace carve (256B aligned) — ~155 MB
    char* w = (char*)d_ws;
    size_t off = 0;
    auto carve = [&](size_t bytes) {
        void* p = w + off;
        off += (bytes + 255) & ~(size_t)255;
        return p;
    };
    bf16*  PX0    = (bf16*) carve((size_t)BN * KP1 * 2);     // 42 MB
    bf16*  X1     = (bf16*) carve((size_t)BN * FP * 2);      // 79.7 MB
    bf16*  Wb1    = (bf16*) carve((size_t)640 * KP1 * 2);
    bf16*  Wb2    = (bf16*) carve((size_t)640 * FP * 2);
    bf16*  Wb3    = (bf16*) carve((size_t)640 * FP * 2);
    bf16*  Wt1t   = (bf16*) carve((size_t)512 * 128 * 2);
    bf16*  Wt2t   = (bf16*) carve((size_t)512 * 512 * 2);
    bf16*  Wet    = (bf16*) carve((size_t)3072 * 512 * 2);
    bf16*  Wh1t   = (bf16*) carve((size_t)640 * FP * 2);
    bf16*  Wh2t   = (bf16*) carve((size_t)640 * FP * 2);
    bf16*  Wh3t   = (bf16*) carve((size_t)384 * FP * 2);
    bf16*  TE     = (bf16*) carve((size_t)B * 128 * 2);
    bf16*  A1b    = (bf16*) carve((size_t)B * 512 * 2);
    bf16*  A2b    = (bf16*) carve((size_t)B * 512 * 2);
    bf16*  EO     = (bf16*) carve((size_t)B * 3000 * 2);
    bf16*  Yv     = (bf16*) carve((size_t)B * FP * 2);
    bf16*  G0     = (bf16*) carve((size_t)B * FP * 2);
    bf16*  G1     = (bf16*) carve((size_t)B * FP * 2);
    bf16*  G2     = (bf16*) carve((size_t)B * FP * 2);
    float* G3     = (float*)carve((size_t)B * 300 * 4);
    bf16*  Pmg    = (bf16*) carve((size_t)512 * 128 * PMS * 2);  // 10.5 MB
    float* qv     = (float*)carve((size_t)BN * 4);
    (void)ws_size; (void)in_sizes; (void)n_in; (void)out_size;

    float* out = (float*)d_out;

    // --- dispatch 1: mega prep ---
    PrepArgs pa;
    struct JD { const float* s; bf16* d; int Ks, Ns, Kp, Np; };
    JD jd[9] = {
        { W_c1, Wb1,  300, 600,  KP1, 640 },
        { W_c2, Wb2,  600, 600,  FP,  640 },
        { W_c3, Wb3,  600, 600,  FP,  640 },
        { W_t1, Wt1t, 128, 512,  128, 512 },
        { W_t2, Wt2t, 512, 512,  512, 512 },
        { W_e,  Wet,  512, 3000, 512, 3072 },
        { W_h1, Wh1t, 600, 600,  FP,  640 },
        { W_h2, Wh2t, 600, 600,  FP,  640 },
        { W_h3, Wh3t, 600, 300,  FP,  384 },
    };
    int cum = 0;
    for (int i = 0; i < 9; ++i) {
        int kt = (jd[i].Kp + 63) >> 6, nt = (jd[i].Np + 63) >> 6;
        pa.j[i] = { jd[i].s, jd[i].d, jd[i].Ks, jd[i].Ns, jd[i].Kp, jd[i].Np, cum };
        cum += kt * nt;
    }
    pa.nwt  = cum;
    pa.te0  = cum;       cum += (B * 128) / 256;
    pa.pp0  = cum;       cum += B / 2;
    pa.xtr0 = cum;       cum += B;
    pa.ei = ei; pa.ts = tst;
    pa.xin = x_in; pa.Wtr = W_tr; pa.btr = b_tr; pa.mask = mask;
    pa.TE = TE; pa.Pmg = Pmg; pa.qv = qv; pa.PX0 = PX0;
    k_prep<<<cum, 256, 0, stream>>>(pa);

    // --- dispatch 2: conv1 plain GEMM (+hidden t1) ---
    conv1_gemm<<<NCONV + 64, 256, 0, stream>>>(
        PX0, Wb1, b_c1, X1,
        TE, 128, Wt1t, 128, b_t1, A1b, 512, 512, 128, 4);

    // --- dispatch 3: conv2+conv3+pool (+hidden t2), P direct-from-L2 ---
    conv_fused_q<<<NCONV + 64, 256, 0, stream>>>(
        X1, FP, FP, Wb2, FP, Pmg, b_c2, qv, Yv,
        A1b, 512, Wt2t, 512, b_t2, A2b, 512, 512, 512, 4);

    // --- dispatch 4: EO || G0 ---
    k_two_gemms<<<464, 256, 0, stream>>>(A2b, Wet, b_e, EO, Yv, Wb3, b_c3, G0);

    // --- h-layers with FiLM (64-row tiles) ---
    gemm64<true, true, bf16><<<dim3(16, 5), 256, 0, stream>>>(
        G0, FP, Wh1t, FP, b_h1, G1, FP, 600, EO + 0, EO + 600, 3000, FP);
    gemm64<true, true, bf16><<<dim3(16, 5), 256, 0, stream>>>(
        G1, FP, Wh2t, FP, b_h2, G2, FP, 600, EO + 1200, EO + 1800, 3000, FP);
    gemm64<false, true, float><<<dim3(16, 3), 256, 0, stream>>>(
        G2, FP, Wh3t, FP, b_h3, G3, 300, 300, EO + 2400, EO + 2700, 3000, FP);

    // --- layer norm + text passthrough ---
    k_ln_copy<<<B, 256, 0, stream>>>(G3, ln_g, ln_b, text, out);
}